// Round 6
// baseline (264.232 us; speedup 1.0000x reference)
//
#include <hip/hip_runtime.h>
#include <math.h>

#define N_NODES 65536
#define NPG     512
#define NGRAPH  128
#define E_EDGES 524288
#define MAXDEG  64
#define NHEADS  8
#define F1      20
#define HID     128
#define D160    160
#define KSEL    256

typedef unsigned short ushort_t;
typedef unsigned int   uint_t;
typedef unsigned long long u64;
typedef __attribute__((ext_vector_type(8))) short short8;
typedef __attribute__((ext_vector_type(4))) float f32x4;

__device__ __forceinline__ float lrelu(float x){ return x > 0.f ? x : 0.2f*x; }
__device__ __forceinline__ ushort_t f2bf(float f){
    uint_t u = __float_as_uint(f);
    return (ushort_t)((u + 0x7FFFu + ((u >> 16) & 1u)) >> 16);
}
__device__ __forceinline__ float bf2f(ushort_t u){ return __uint_as_float(((uint_t)u) << 16); }
__device__ __forceinline__ float bflo(uint_t v){ return __uint_as_float(v << 16); }
__device__ __forceinline__ float bfhi(uint_t v){ return __uint_as_float(v & 0xFFFF0000u); }
// XCD-coherent block swizzle: graph tiles pinned to one XCD across ALL kernels.
__device__ __forceinline__ int xswz(int bid, int nblocks){
    return (bid & 7) * (nblocks >> 3) + (bid >> 3);
}
__device__ __forceinline__ float rdlanef(float v, int i){
    return __uint_as_float((uint_t)__builtin_amdgcn_readlane(__float_as_int(v), i));
}

// sortable composite: desc score, tie -> asc idx
__device__ __forceinline__ u64 comp_make(float s, int idx){
    uint_t u = __float_as_uint(s);
    u ^= (u & 0x80000000u) ? 0xFFFFFFFFu : 0x80000000u;
    return ((u64)u << 32) | (u64)(511 - idx);
}
__device__ __forceinline__ float comp_score(u64 c){
    uint_t u = (uint_t)(c >> 32);
    u ^= (u & 0x80000000u) ? 0x80000000u : 0xFFFFFFFFu;
    return __uint_as_float(u);
}
__device__ __forceinline__ int comp_idx(u64 c){ return 511 - (int)(c & 0x1FFu); }
__device__ __forceinline__ u64 shfl_xor_u64(u64 x, int m){
    uint_t lo = __shfl_xor((uint_t)x, m);
    uint_t hi = __shfl_xor((uint_t)(x >> 32), m);
    return ((u64)hi << 32) | lo;
}

// ---------------- ELL adjacency build (dst -> list of src) ----------------
__global__ void k_build_ell(const int* __restrict__ src, const int* __restrict__ dst,
                            int* __restrict__ deg, int* __restrict__ ell){
    int blk = xswz(blockIdx.x, E_EDGES/256);
    int e = blk*blockDim.x + threadIdx.x;
    int d = dst[e];
    int p = atomicAdd(&deg[d], 1);
    if(p < MAXDEG) ell[d*MAXDEG + p] = src[e];
}

// ---------------- conv A1: z (bf16) from one-hot gather + es/ed dots ----------------
__global__ void k_a1_z(const int* __restrict__ x, const float* __restrict__ W,
                       const float* __restrict__ asrc, const float* __restrict__ adst,
                       ushort_t* __restrict__ z8, float* __restrict__ es8, float* __restrict__ ed8){
    int blk = xswz(blockIdx.x, N_NODES*NHEADS/256);
    int t = blk*blockDim.x + threadIdx.x;
    int n = t >> 3, h = t & 7;
    int lbl = x[n];
    const float* wrow = W + lbl*D160 + h*F1;
    const float* as = asrc + h*F1;
    const float* ad = adst + h*F1;
    uint_t* zr = (uint_t*)(z8 + (size_t)n*D160 + h*F1);
    float es = 0.f, ed = 0.f;
    #pragma unroll
    for(int f=0; f<10; ++f){
        float v0 = wrow[2*f], v1 = wrow[2*f+1];
        zr[f] = (uint_t)f2bf(v0) | ((uint_t)f2bf(v1) << 16);
        es += v0*as[2*f] + v1*as[2*f+1];
        ed += v0*ad[2*f] + v1*ad[2*f+1];
    }
    es8[t] = es; ed8[t] = ed;
}

// ---------------- 8-head attention: 2 heads per thread, dwordx4 z loads ----------------
__global__ void k_attn8(const int* __restrict__ deg, const int* __restrict__ ell,
                        const ushort_t* __restrict__ z8, const float* __restrict__ es8,
                        const float* __restrict__ ed8, const float* __restrict__ bias,
                        ushort_t* __restrict__ out){
    int blk = xswz(blockIdx.x, N_NODES*4/256);
    int p = blk*blockDim.x + threadIdx.x;
    int n = p >> 2, hp = p & 3;            // heads 2hp, 2hp+1
    int dg = deg[n]; if(dg > MAXDEG) dg = MAXDEG;
    float2 edn = *(const float2*)(ed8 + (size_t)n*8 + hp*2);
    float2 esn = *(const float2*)(es8 + (size_t)n*8 + hp*2);
    float ese0 = lrelu(esn.x + edn.x), ese1 = lrelu(esn.y + edn.y);
    const int* el = ell + n*MAXDEG;
    float m0 = ese0, m1 = ese1;
    {
        int i = 0;
        for(; i+2 <= dg; i += 2){
            int sa = el[i], sb = el[i+1];
            float2 ea = *(const float2*)(es8 + (size_t)sa*8 + hp*2);
            float2 eb = *(const float2*)(es8 + (size_t)sb*8 + hp*2);
            m0 = fmaxf(m0, fmaxf(lrelu(ea.x + edn.x), lrelu(eb.x + edn.x)));
            m1 = fmaxf(m1, fmaxf(lrelu(ea.y + edn.y), lrelu(eb.y + edn.y)));
        }
        if(i < dg){
            float2 ea = *(const float2*)(es8 + (size_t)el[i]*8 + hp*2);
            m0 = fmaxf(m0, lrelu(ea.x + edn.x));
            m1 = fmaxf(m1, lrelu(ea.y + edn.y));
        }
    }
    float w0 = expf(ese0 - m0), w1 = expf(ese1 - m1);
    float den0 = w0, den1 = w1;
    float acc[40];
    {
        const uint4* zn = (const uint4*)(z8 + (size_t)n*D160 + hp*40);
        #pragma unroll
        for(int q=0; q<5; ++q){
            uint4 v = zn[q];
            const uint_t* vu = (const uint_t*)&v;
            #pragma unroll
            for(int r=0; r<4; ++r){
                int ch = q*8 + r*2;
                float w = (ch < 20) ? w0 : w1;
                float wN = (ch+1 < 20) ? w0 : w1;
                acc[ch]   = w *bflo(vu[r]);
                acc[ch+1] = wN*bfhi(vu[r]);
            }
        }
    }
    {
        int i = 0;
        for(; i+2 <= dg; i += 2){
            int sa = el[i], sb = el[i+1];
            float2 ea = *(const float2*)(es8 + (size_t)sa*8 + hp*2);
            float2 eb = *(const float2*)(es8 + (size_t)sb*8 + hp*2);
            const uint4* za = (const uint4*)(z8 + (size_t)sa*D160 + hp*40);
            const uint4* zb = (const uint4*)(z8 + (size_t)sb*D160 + hp*40);
            uint4 va[5], vb[5];
            #pragma unroll
            for(int q=0;q<5;++q){ va[q] = za[q]; vb[q] = zb[q]; }
            float wa0 = expf(lrelu(ea.x + edn.x) - m0);
            float wa1 = expf(lrelu(ea.y + edn.y) - m1);
            float wb0 = expf(lrelu(eb.x + edn.x) - m0);
            float wb1 = expf(lrelu(eb.y + edn.y) - m1);
            den0 += wa0 + wb0; den1 += wa1 + wb1;
            #pragma unroll
            for(int q=0; q<5; ++q){
                const uint_t* au = (const uint_t*)&va[q];
                const uint_t* bu = (const uint_t*)&vb[q];
                #pragma unroll
                for(int r=0; r<4; ++r){
                    int ch = q*8 + r*2;
                    float wA  = (ch   < 20) ? wa0 : wa1;
                    float wB  = (ch   < 20) ? wb0 : wb1;
                    float wAn = (ch+1 < 20) ? wa0 : wa1;
                    float wBn = (ch+1 < 20) ? wb0 : wb1;
                    acc[ch]   += wA *bflo(au[r]) + wB *bflo(bu[r]);
                    acc[ch+1] += wAn*bfhi(au[r]) + wBn*bfhi(bu[r]);
                }
            }
        }
        if(i < dg){
            int sa = el[i];
            float2 ea = *(const float2*)(es8 + (size_t)sa*8 + hp*2);
            const uint4* za = (const uint4*)(z8 + (size_t)sa*D160 + hp*40);
            uint4 va[5];
            #pragma unroll
            for(int q=0;q<5;++q) va[q] = za[q];
            float wa0 = expf(lrelu(ea.x + edn.x) - m0);
            float wa1 = expf(lrelu(ea.y + edn.y) - m1);
            den0 += wa0; den1 += wa1;
            #pragma unroll
            for(int q=0; q<5; ++q){
                const uint_t* au = (const uint_t*)&va[q];
                #pragma unroll
                for(int r=0; r<4; ++r){
                    int ch = q*8 + r*2;
                    float wA  = (ch   < 20) ? wa0 : wa1;
                    float wAn = (ch+1 < 20) ? wa0 : wa1;
                    acc[ch]   += wA *bflo(au[r]);
                    acc[ch+1] += wAn*bfhi(au[r]);
                }
            }
        }
    }
    float inv0 = 1.f/(den0 + 1e-16f);
    float inv1 = 1.f/(den1 + 1e-16f);
    const float* bb = bias + hp*40;
    uint4 ov[5];
    #pragma unroll
    for(int q=0; q<5; ++q){
        uint_t* ou = (uint_t*)&ov[q];
        #pragma unroll
        for(int r=0; r<4; ++r){
            int ch = q*8 + r*2;
            float i0 = (ch   < 20) ? inv0 : inv1;
            float i1 = (ch+1 < 20) ? inv0 : inv1;
            float v0 = fmaxf(acc[ch]*i0   + bb[ch],   0.f);
            float v1 = fmaxf(acc[ch+1]*i1 + bb[ch+1], 0.f);
            ou[r] = (uint_t)f2bf(v0) | ((uint_t)f2bf(v1) << 16);
        }
    }
    uint4* o = (uint4*)(out + (size_t)n*D160 + hp*40);
    #pragma unroll
    for(int q=0; q<5; ++q) o[q] = ov[q];
}

// ---------------- bf16 MFMA GEMM + optional fused row-dot epilogue ----------------
template<int IN, int OUT, bool DOT>
__global__ __launch_bounds__(256) void k_gemm_mfma(const ushort_t* __restrict__ A,
                                                   const float* __restrict__ W,
                                                   ushort_t* __restrict__ C,
                                                   const float* __restrict__ va,
                                                   const float* __restrict__ vb,
                                                   float* __restrict__ oa,
                                                   float* __restrict__ ob){
    constexpr int NT = OUT/16;
    constexpr int KS = IN/32;
    constexpr int LDW = IN + 8;
    __shared__ __align__(16) ushort_t Wt[OUT*LDW];
    int tid = threadIdx.x;
    for(int i = tid; i < IN*OUT; i += 256){
        int k = i / OUT, n = i - k*OUT;
        Wt[n*LDW + k] = f2bf(W[i]);
    }
    __syncthreads();
    int blk = xswz(blockIdx.x, N_NODES/64);
    int wave = tid >> 6, lane = tid & 63;
    int col16 = lane & 15;
    int kq = (lane >> 4) * 8;
    int row = blk*64 + wave*16 + col16;
    const ushort_t* Ar = A + (size_t)row*IN + kq;
    f32x4 acc[NT];
    #pragma unroll
    for(int c=0;c<NT;++c) acc[c] = (f32x4){0.f,0.f,0.f,0.f};
    #pragma unroll
    for(int ks=0; ks<KS; ++ks){
        short8 af = *reinterpret_cast<const short8*>(Ar + ks*32);
        #pragma unroll
        for(int c=0;c<NT;++c){
            short8 bf = *reinterpret_cast<const short8*>(&Wt[(c*16 + col16)*LDW + ks*32 + kq]);
            acc[c] = __builtin_amdgcn_mfma_f32_16x16x32_bf16(af, bf, acc[c], 0, 0, 0);
        }
    }
    int rbase = blk*64 + wave*16 + (lane >> 4)*4;
    #pragma unroll
    for(int c=0;c<NT;++c){
        #pragma unroll
        for(int r=0;r<4;++r){
            C[(size_t)(rbase + r)*OUT + c*16 + col16] = f2bf(acc[c][r]);
        }
    }
    if(DOT){
        float pa[4] = {0,0,0,0}, pb[4] = {0,0,0,0};
        #pragma unroll
        for(int c=0;c<NT;++c){
            float a = va[c*16 + col16];
            float b = vb[c*16 + col16];
            #pragma unroll
            for(int r=0;r<4;++r){ pa[r] += acc[c][r]*a; pb[r] += acc[c][r]*b; }
        }
        #pragma unroll
        for(int o=1;o<16;o<<=1){
            #pragma unroll
            for(int r=0;r<4;++r){ pa[r] += __shfl_xor(pa[r], o); pb[r] += __shfl_xor(pb[r], o); }
        }
        if(col16 == 0){
            #pragma unroll
            for(int r=0;r<4;++r){ oa[rbase + r] = pa[r]; ob[rbase + r] = pb[r]; }
        }
    }
}

// ---------------- B1 GEMM with 16 extra weight columns = fused es8/ed8 ----------------
// es[n,h] = Sum_f z[n,h*20+f]*asrc[h,f] = (A @ (W@S))[n,h]; 16 extra bf16 cols in LDS.
__global__ __launch_bounds__(256) void k_gemm_b1(const ushort_t* __restrict__ A,
                                                 const float* __restrict__ W,
                                                 const float* __restrict__ asrc,
                                                 const float* __restrict__ adst,
                                                 ushort_t* __restrict__ C,
                                                 float* __restrict__ es8,
                                                 float* __restrict__ ed8){
    constexpr int IN = HID, OUTW = D160, NT = 11, KS = IN/32, LDW = IN + 8;
    __shared__ __align__(16) ushort_t Wt[(OUTW+16)*LDW];
    int tid = threadIdx.x;
    for(int i = tid; i < IN*OUTW; i += 256){
        int k = i / OUTW, n = i - k*OUTW;
        Wt[n*LDW + k] = f2bf(W[i]);
    }
    for(int i = tid; i < IN*16; i += 256){
        int k = i >> 4, j = i & 15;
        const float* av = (j < 8 ? asrc : adst) + (j & 7)*F1;
        const float* wr = W + k*OUTW + (j & 7)*F1;
        float s = 0.f;
        #pragma unroll
        for(int f=0; f<F1; ++f) s += wr[f]*av[f];
        Wt[(OUTW + j)*LDW + k] = f2bf(s);
    }
    __syncthreads();
    int blk = xswz(blockIdx.x, N_NODES/64);
    int wave = tid >> 6, lane = tid & 63;
    int col16 = lane & 15;
    int kq = (lane >> 4) * 8;
    int row = blk*64 + wave*16 + col16;
    const ushort_t* Ar = A + (size_t)row*IN + kq;
    f32x4 acc[NT];
    #pragma unroll
    for(int c=0;c<NT;++c) acc[c] = (f32x4){0.f,0.f,0.f,0.f};
    #pragma unroll
    for(int ks=0; ks<KS; ++ks){
        short8 af = *reinterpret_cast<const short8*>(Ar + ks*32);
        #pragma unroll
        for(int c=0;c<NT;++c){
            short8 bf = *reinterpret_cast<const short8*>(&Wt[(c*16 + col16)*LDW + ks*32 + kq]);
            acc[c] = __builtin_amdgcn_mfma_f32_16x16x32_bf16(af, bf, acc[c], 0, 0, 0);
        }
    }
    int rbase = blk*64 + wave*16 + (lane >> 4)*4;
    #pragma unroll
    for(int c=0;c<10;++c){
        #pragma unroll
        for(int r=0;r<4;++r){
            C[(size_t)(rbase + r)*OUTW + c*16 + col16] = f2bf(acc[c][r]);
        }
    }
    // extra col fragment: col16<8 -> es head col16 ; col16>=8 -> ed head col16-8
    #pragma unroll
    for(int r=0;r<4;++r){
        float v = acc[10][r];
        if(col16 < 8) es8[(size_t)(rbase + r)*8 + col16] = v;
        else          ed8[(size_t)(rbase + r)*8 + (col16 - 8)] = v;
    }
}

// ---------------- 1-head attention aggregate (wave per node), bf16 Z ----------------
template<typename OutT, bool DOT>
__global__ void k_attn1(const int* __restrict__ deg, const int* __restrict__ ell,
                        const ushort_t* __restrict__ Z, const float* __restrict__ es,
                        const float* __restrict__ ed, const float* __restrict__ bias,
                        OutT* __restrict__ out,
                        const float* __restrict__ wa, const float* __restrict__ wb,
                        float* __restrict__ oa, float* __restrict__ ob){
    int blk = xswz(blockIdx.x, N_NODES/4);
    int gt = blk*blockDim.x + threadIdx.x;
    int n = gt >> 6;
    int l = threadIdx.x & 63;
    int dg = deg[n]; if(dg > MAXDEG) dg = MAXDEG;
    float edn = ed[n];
    float eself = lrelu(es[n] + edn);
    int s_l = 0; float e_l = -1e30f;
    if(l < dg){ s_l = ell[n*MAXDEG + l]; e_l = lrelu(es[s_l] + edn); }
    float m = fmaxf(e_l, eself);
    for(int o=32;o>0;o>>=1) m = fmaxf(m, __shfl_xor(m,o));
    float w_l = (l < dg) ? expf(e_l - m) : 0.f;
    float den = w_l;
    for(int o=32;o>0;o>>=1) den += __shfl_xor(den,o);
    float wself = expf(eself - m);
    den += wself;
    const uint_t* Zu = (const uint_t*)Z;
    uint_t zn = Zu[(size_t)n*64 + l];
    float acc0 = wself*bflo(zn);
    float acc1 = wself*bfhi(zn);
    int i = 0;
    for(; i+4 <= dg; i += 4){
        int s0 = __builtin_amdgcn_readlane(s_l, i);
        int s1 = __builtin_amdgcn_readlane(s_l, i+1);
        int s2 = __builtin_amdgcn_readlane(s_l, i+2);
        int s3 = __builtin_amdgcn_readlane(s_l, i+3);
        uint_t z0 = Zu[(size_t)s0*64 + l];
        uint_t z1 = Zu[(size_t)s1*64 + l];
        uint_t z2 = Zu[(size_t)s2*64 + l];
        uint_t z3 = Zu[(size_t)s3*64 + l];
        float w0 = rdlanef(w_l, i);
        float w1 = rdlanef(w_l, i+1);
        float w2 = rdlanef(w_l, i+2);
        float w3 = rdlanef(w_l, i+3);
        acc0 += w0*bflo(z0) + w1*bflo(z1);
        acc1 += w0*bfhi(z0) + w1*bfhi(z1);
        acc0 += w2*bflo(z2) + w3*bflo(z3);
        acc1 += w2*bfhi(z2) + w3*bfhi(z3);
    }
    for(; i < dg; ++i){
        int s0 = __builtin_amdgcn_readlane(s_l, i);
        float w0 = rdlanef(w_l, i);
        uint_t z0 = Zu[(size_t)s0*64 + l];
        acc0 += w0*bflo(z0);
        acc1 += w0*bfhi(z0);
    }
    float inv = 1.f/(den + 1e-16f);
    float2 bb = ((const float2*)bias)[l];
    float r0 = fmaxf(acc0*inv + bb.x, 0.f);
    float r1 = fmaxf(acc1*inv + bb.y, 0.f);
    if(sizeof(OutT) == 2){
        ((uint_t*)out)[(size_t)n*64 + l] = (uint_t)f2bf(r0) | ((uint_t)f2bf(r1) << 16);
    } else {
        float2 rv; rv.x = r0; rv.y = r1;
        ((float2*)out)[(size_t)n*64 + l] = rv;
    }
    if(DOT){
        float2 a2 = ((const float2*)wa)[l];
        float2 b2 = ((const float2*)wb)[l];
        float pa = r0*a2.x + r1*a2.y;
        float pb = r0*b2.x + r1*b2.y;
        for(int o=32;o>0;o>>=1){ pa += __shfl_xor(pa,o); pb += __shfl_xor(pb,o); }
        if(l==0){ oa[n] = pa; ob[n] = pb; }
    }
}

// ---------------- per-graph fused score + top-k + pooled max ----------------
__global__ __launch_bounds__(512) void k_topk_pool(const int* __restrict__ deg,
                                                   const int* __restrict__ ell,
                                                   const float* __restrict__ yrel,
                                                   const float* __restrict__ rroot,
                                                   const float* __restrict__ bpool,
                                                   const float* __restrict__ H,
                                                   float* __restrict__ pooled,
                                                   float* __restrict__ perm_f,
                                                   float* __restrict__ sv,
                                                   float* __restrict__ batch_f){
    __shared__ float ssc[NPG];
    __shared__ int   sidx[KSEL];
    __shared__ float sval[KSEL];
    __shared__ float pmax[512];
    int g = xswz(blockIdx.x, NGRAPH);
    int base = g*NPG;
    int t = threadIdx.x;
    // fused score
    {
        int n = base + t;
        int dg = deg[n]; if(dg > MAXDEG) dg = MAXDEG;
        float s = rroot[n] + bpool[0];
        const int* el = ell + n*MAXDEG;
        int i = 0;
        for(; i+4 <= dg; i += 4){
            float y0 = yrel[el[i]],   y1 = yrel[el[i+1]];
            float y2 = yrel[el[i+2]], y3 = yrel[el[i+3]];
            s += (y0 + y1) + (y2 + y3);
        }
        for(; i < dg; ++i) s += yrel[el[i]];
        ssc[t] = tanhf(s);
    }
    __syncthreads();
    if(t < 64){
        int l = t;
        u64 v[8];
        #pragma unroll
        for(int r=0;r<8;++r){
            int i = r*64 + l;
            v[r] = comp_make(ssc[i], i);
        }
        #pragma unroll
        for(int kk=1; kk<=9; ++kk){
            int k = 1 << kk;
            #pragma unroll
            for(int jj=kk-1; jj>=0; --jj){
                int j = 1 << jj;
                if(j < 64){
                    bool lower = (l & j) == 0;
                    #pragma unroll
                    for(int r=0;r<8;++r){
                        int i = r*64 + l;
                        u64 p = shfl_xor_u64(v[r], j);
                        bool desc = (i & k) == 0;
                        u64 mx = v[r] > p ? v[r] : p;
                        u64 mn = v[r] > p ? p : v[r];
                        v[r] = (lower == desc) ? mx : mn;
                    }
                } else {
                    int jr = j >> 6;
                    #pragma unroll
                    for(int r=0;r<8;++r){
                        if((r & jr) == 0){
                            int rp = r | jr;
                            int i = r*64 + l;
                            bool desc = (i & k) == 0;
                            u64 a = v[r], b = v[rp];
                            u64 mx = a > b ? a : b;
                            u64 mn = a > b ? b : a;
                            v[r]  = desc ? mx : mn;
                            v[rp] = desc ? mn : mx;
                        }
                    }
                }
            }
        }
        #pragma unroll
        for(int r=0;r<4;++r){
            int i = r*64 + l;
            int idx = comp_idx(v[r]);
            float s = comp_score(v[r]);
            perm_f[g*KSEL + i]  = (float)(base + idx);
            sv[g*KSEL + i]      = s;
            batch_f[g*KSEL + i] = (float)g;
            sidx[i] = idx; sval[i] = s;
        }
    }
    __syncthreads();
    int c = t & 127, kc = t >> 7;
    float mx = -1e30f;
    for(int kk = kc*64; kk < kc*64 + 64; ++kk){
        mx = fmaxf(mx, H[(size_t)(base + sidx[kk])*HID + c] * sval[kk]);
    }
    pmax[t] = mx;
    __syncthreads();
    if(t < HID){
        pooled[g*HID + t] = fmaxf(fmaxf(pmax[t], pmax[t+128]),
                                  fmaxf(pmax[t+256], pmax[t+384]));
    }
}

extern "C" void kernel_launch(void* const* d_in, const int* in_sizes, int n_in,
                              void* d_out, int out_size, void* d_ws, size_t ws_size,
                              hipStream_t stream) {
    const int*   x       = (const int*)  d_in[0];
    const int*   eidx    = (const int*)  d_in[1];
    const float* W_a1    = (const float*)d_in[3];
    const float* asrc_a1 = (const float*)d_in[4];
    const float* adst_a1 = (const float*)d_in[5];
    const float* b_a1    = (const float*)d_in[6];
    const float* W_a2    = (const float*)d_in[7];
    const float* asrc_a2 = (const float*)d_in[8];
    const float* adst_a2 = (const float*)d_in[9];
    const float* b_a2    = (const float*)d_in[10];
    const float* W_b1    = (const float*)d_in[11];
    const float* asrc_b1 = (const float*)d_in[12];
    const float* adst_b1 = (const float*)d_in[13];
    const float* b_b1    = (const float*)d_in[14];
    const float* W_b2    = (const float*)d_in[15];
    const float* asrc_b2 = (const float*)d_in[16];
    const float* adst_b2 = (const float*)d_in[17];
    const float* b_b2    = (const float*)d_in[18];
    const float* w_rel   = (const float*)d_in[19];
    const float* w_root  = (const float*)d_in[20];
    const float* b_pool  = (const float*)d_in[21];

    const int* e_src = eidx;
    const int* e_dst = eidx + E_EDGES;

    char* ws = (char*)d_ws;
    size_t off = 0;
    auto alloc = [&](size_t bytes)->char*{
        char* p = ws + off;
        off += (bytes + 255) & ~(size_t)255;
        return p;
    };
    int*      deg   = (int*)     alloc((size_t)N_NODES*4);
    int*      ell   = (int*)     alloc((size_t)N_NODES*MAXDEG*4);
    ushort_t* z8    = (ushort_t*)alloc((size_t)N_NODES*D160*2);
    ushort_t* h8    = (ushort_t*)alloc((size_t)N_NODES*D160*2);
    ushort_t* zc    = (ushort_t*)alloc((size_t)N_NODES*HID*2);
    ushort_t* hmid  = (ushort_t*)alloc((size_t)N_NODES*HID*2);
    float*    hfin  = (float*)   alloc((size_t)N_NODES*HID*4);
    float*    es8   = (float*)   alloc((size_t)N_NODES*NHEADS*4);
    float*    ed8   = (float*)   alloc((size_t)N_NODES*NHEADS*4);
    float*    es1   = (float*)   alloc((size_t)N_NODES*4);
    float*    ed1   = (float*)   alloc((size_t)N_NODES*4);
    float*    yrel  = (float*)   alloc((size_t)N_NODES*4);
    float*    rroot = (float*)   alloc((size_t)N_NODES*4);
    (void)ws_size; (void)n_in; (void)in_sizes; (void)out_size;

    float* out      = (float*)d_out;
    float* pooled   = out;
    float* perm_f   = out + NGRAPH*HID;
    float* sv       = perm_f + NGRAPH*KSEL;
    float* batch_f  = sv + NGRAPH*KSEL;

    hipMemsetAsync(deg, 0, (size_t)N_NODES*4, stream);
    k_build_ell<<<E_EDGES/256, 256, 0, stream>>>(e_src, e_dst, deg, ell);

    // ---- GATNet A, conv1 (one-hot gather -> 20x8) ----
    k_a1_z<<<N_NODES*NHEADS/256, 256, 0, stream>>>(x, W_a1, asrc_a1, adst_a1, z8, es8, ed8);
    k_attn8<<<N_NODES*4/256, 256, 0, stream>>>(deg, ell, z8, es8, ed8, b_a1, h8);

    // ---- GATNet A, conv2 (160 -> 128) + fused es/ed dots ----
    k_gemm_mfma<D160, HID, true><<<N_NODES/64, 256, 0, stream>>>(h8, W_a2, zc, asrc_a2, adst_a2, es1, ed1);
    k_attn1<ushort_t, false><<<N_NODES/4, 256, 0, stream>>>(deg, ell, zc, es1, ed1, b_a2, hmid,
                                                            nullptr, nullptr, nullptr, nullptr);

    // ---- GATNet B, conv1 (128 -> 20x8) + fused es8/ed8 via extended weight ----
    k_gemm_b1<<<N_NODES/64, 256, 0, stream>>>(hmid, W_b1, asrc_b1, adst_b1, z8, es8, ed8);
    k_attn8<<<N_NODES*4/256, 256, 0, stream>>>(deg, ell, z8, es8, ed8, b_b1, h8);

    // ---- GATNet B, conv2 (160 -> 128) + fused es/ed dots ----
    k_gemm_mfma<D160, HID, true><<<N_NODES/64, 256, 0, stream>>>(h8, W_b2, zc, asrc_b2, adst_b2, es1, ed1);
    // final attention + fused pooling dots (yrel, rroot)
    k_attn1<float, true><<<N_NODES/4, 256, 0, stream>>>(deg, ell, zc, es1, ed1, b_b2, hfin,
                                                        w_rel, w_root, yrel, rroot);

    // ---- SAGPooling: fused score + top-k + pool ----
    k_topk_pool<<<NGRAPH, NPG, 0, stream>>>(deg, ell, yrel, rroot, b_pool, hfin,
                                            pooled, perm_f, sv, batch_f);
}

// Round 7
// 256.644 us; speedup vs baseline: 1.0296x; 1.0296x over previous
//
#include <hip/hip_runtime.h>
#include <math.h>

#define N_NODES 65536
#define NPG     512
#define NGRAPH  128
#define E_EDGES 524288
#define MAXDEG  64
#define NHEADS  8
#define F1      20
#define HID     128
#define D160    160
#define KSEL    256

typedef unsigned short ushort_t;
typedef unsigned int   uint_t;
typedef unsigned long long u64;
typedef __attribute__((ext_vector_type(8))) short short8;
typedef __attribute__((ext_vector_type(4))) float f32x4;

__device__ __forceinline__ float lrelu(float x){ return x > 0.f ? x : 0.2f*x; }
__device__ __forceinline__ ushort_t f2bf(float f){
    uint_t u = __float_as_uint(f);
    return (ushort_t)((u + 0x7FFFu + ((u >> 16) & 1u)) >> 16);
}
__device__ __forceinline__ float bf2f(ushort_t u){ return __uint_as_float(((uint_t)u) << 16); }
__device__ __forceinline__ float bflo(uint_t v){ return __uint_as_float(v << 16); }
__device__ __forceinline__ float bfhi(uint_t v){ return __uint_as_float(v & 0xFFFF0000u); }
// XCD-coherent block swizzle: graph tiles pinned to one XCD across ALL kernels.
__device__ __forceinline__ int xswz(int bid, int nblocks){
    return (bid & 7) * (nblocks >> 3) + (bid >> 3);
}
__device__ __forceinline__ float rdlanef(float v, int i){
    return __uint_as_float((uint_t)__builtin_amdgcn_readlane(__float_as_int(v), i));
}

// sortable composite: desc score, tie -> asc idx
__device__ __forceinline__ u64 comp_make(float s, int idx){
    uint_t u = __float_as_uint(s);
    u ^= (u & 0x80000000u) ? 0xFFFFFFFFu : 0x80000000u;
    return ((u64)u << 32) | (u64)(511 - idx);
}
__device__ __forceinline__ float comp_score(u64 c){
    uint_t u = (uint_t)(c >> 32);
    u ^= (u & 0x80000000u) ? 0x80000000u : 0xFFFFFFFFu;
    return __uint_as_float(u);
}
__device__ __forceinline__ int comp_idx(u64 c){ return 511 - (int)(c & 0x1FFu); }
__device__ __forceinline__ u64 shfl_xor_u64(u64 x, int m){
    uint_t lo = __shfl_xor((uint_t)x, m);
    uint_t hi = __shfl_xor((uint_t)(x >> 32), m);
    return ((u64)hi << 32) | lo;
}

// ---------------- fast zero (rocclr fillBuffer is ~43us for 256KB!) ----------------
__global__ void k_zero(uint4* __restrict__ p){
    p[blockIdx.x*blockDim.x + threadIdx.x] = (uint4){0,0,0,0};
}

// ---------------- ELL adjacency build (dst -> list of src) ----------------
__global__ void k_build_ell(const int* __restrict__ src, const int* __restrict__ dst,
                            int* __restrict__ deg, int* __restrict__ ell){
    int blk = xswz(blockIdx.x, E_EDGES/256);
    int e = blk*blockDim.x + threadIdx.x;
    int d = dst[e];
    int p = atomicAdd(&deg[d], 1);
    if(p < MAXDEG) ell[d*MAXDEG + p] = src[e];
}

// ---------------- conv A1: z (bf16) from one-hot gather + es/ed dots ----------------
__global__ void k_a1_z(const int* __restrict__ x, const float* __restrict__ W,
                       const float* __restrict__ asrc, const float* __restrict__ adst,
                       ushort_t* __restrict__ z8, float* __restrict__ es8, float* __restrict__ ed8){
    int blk = xswz(blockIdx.x, N_NODES*NHEADS/256);
    int t = blk*blockDim.x + threadIdx.x;
    int n = t >> 3, h = t & 7;
    int lbl = x[n];
    const float* wrow = W + lbl*D160 + h*F1;
    const float* as = asrc + h*F1;
    const float* ad = adst + h*F1;
    uint_t* zr = (uint_t*)(z8 + (size_t)n*D160 + h*F1);
    float es = 0.f, ed = 0.f;
    #pragma unroll
    for(int f=0; f<10; ++f){
        float v0 = wrow[2*f], v1 = wrow[2*f+1];
        zr[f] = (uint_t)f2bf(v0) | ((uint_t)f2bf(v1) << 16);
        es += v0*as[2*f] + v1*as[2*f+1];
        ed += v0*ad[2*f] + v1*ad[2*f+1];
    }
    es8[t] = es; ed8[t] = ed;
}

// ---------------- 8-head attention aggregate (thread per node,head), bf16 z ----------------
__global__ void k_attn8(const int* __restrict__ deg, const int* __restrict__ ell,
                        const ushort_t* __restrict__ z8, const float* __restrict__ es8,
                        const float* __restrict__ ed8, const float* __restrict__ bias,
                        ushort_t* __restrict__ out){
    int blk = xswz(blockIdx.x, N_NODES*NHEADS/256);
    int t = blk*blockDim.x + threadIdx.x;
    int n = t >> 3, h = t & 7;
    int dg = deg[n]; if(dg > MAXDEG) dg = MAXDEG;
    float edn = ed8[t];
    float eself = lrelu(es8[t] + edn);
    const int* el = ell + n*MAXDEG;
    float m = eself;
    {
        int i = 0;
        for(; i+2 <= dg; i += 2){
            int sa = el[i], sb = el[i+1];
            float ea = es8[sa*NHEADS + h], eb = es8[sb*NHEADS + h];
            m = fmaxf(m, fmaxf(lrelu(ea + edn), lrelu(eb + edn)));
        }
        if(i < dg){
            float ea = es8[el[i]*NHEADS + h];
            m = fmaxf(m, lrelu(ea + edn));
        }
    }
    float w = expf(eself - m);
    float den = w;
    float acc[F1];
    const uint_t* zn = (const uint_t*)(z8 + (size_t)n*D160 + h*F1);
    #pragma unroll
    for(int f=0; f<10; ++f){
        uint_t v = zn[f];
        acc[2*f]   = w*bflo(v);
        acc[2*f+1] = w*bfhi(v);
    }
    {
        int i = 0;
        for(; i+2 <= dg; i += 2){
            int sa = el[i], sb = el[i+1];
            float ea = es8[sa*NHEADS + h], eb = es8[sb*NHEADS + h];
            const uint_t* za = (const uint_t*)(z8 + (size_t)sa*D160 + h*F1);
            const uint_t* zb = (const uint_t*)(z8 + (size_t)sb*D160 + h*F1);
            float wa = expf(lrelu(ea + edn) - m);
            float wb = expf(lrelu(eb + edn) - m);
            den += wa + wb;
            #pragma unroll
            for(int f=0; f<10; ++f){
                uint_t va = za[f], vb = zb[f];
                acc[2*f]   += wa*bflo(va) + wb*bflo(vb);
                acc[2*f+1] += wa*bfhi(va) + wb*bfhi(vb);
            }
        }
        if(i < dg){
            int sa = el[i];
            float ea = es8[sa*NHEADS + h];
            const uint_t* za = (const uint_t*)(z8 + (size_t)sa*D160 + h*F1);
            float wa = expf(lrelu(ea + edn) - m);
            den += wa;
            #pragma unroll
            for(int f=0; f<10; ++f){
                uint_t va = za[f];
                acc[2*f]   += wa*bflo(va);
                acc[2*f+1] += wa*bfhi(va);
            }
        }
    }
    float inv = 1.f/(den + 1e-16f);
    uint_t* o = (uint_t*)(out + (size_t)n*D160 + h*F1);
    const float* bb = bias + h*F1;
    #pragma unroll
    for(int f=0; f<10; ++f){
        float v0 = fmaxf(acc[2*f]*inv   + bb[2*f],   0.f);
        float v1 = fmaxf(acc[2*f+1]*inv + bb[2*f+1], 0.f);
        o[f] = (uint_t)f2bf(v0) | ((uint_t)f2bf(v1) << 16);
    }
}

// ---------------- bf16 MFMA GEMM + optional fused row-dot epilogue ----------------
template<int IN, int OUT, bool DOT>
__global__ __launch_bounds__(256) void k_gemm_mfma(const ushort_t* __restrict__ A,
                                                   const float* __restrict__ W,
                                                   ushort_t* __restrict__ C,
                                                   const float* __restrict__ va,
                                                   const float* __restrict__ vb,
                                                   float* __restrict__ oa,
                                                   float* __restrict__ ob){
    constexpr int NT = OUT/16;
    constexpr int KS = IN/32;
    constexpr int LDW = IN + 8;
    __shared__ __align__(16) ushort_t Wt[OUT*LDW];
    int tid = threadIdx.x;
    for(int i = tid; i < IN*OUT; i += 256){
        int k = i / OUT, n = i - k*OUT;
        Wt[n*LDW + k] = f2bf(W[i]);
    }
    __syncthreads();
    int blk = xswz(blockIdx.x, N_NODES/64);
    int wave = tid >> 6, lane = tid & 63;
    int col16 = lane & 15;
    int kq = (lane >> 4) * 8;
    int row = blk*64 + wave*16 + col16;
    const ushort_t* Ar = A + (size_t)row*IN + kq;
    f32x4 acc[NT];
    #pragma unroll
    for(int c=0;c<NT;++c) acc[c] = (f32x4){0.f,0.f,0.f,0.f};
    #pragma unroll
    for(int ks=0; ks<KS; ++ks){
        short8 af = *reinterpret_cast<const short8*>(Ar + ks*32);
        #pragma unroll
        for(int c=0;c<NT;++c){
            short8 bf = *reinterpret_cast<const short8*>(&Wt[(c*16 + col16)*LDW + ks*32 + kq]);
            acc[c] = __builtin_amdgcn_mfma_f32_16x16x32_bf16(af, bf, acc[c], 0, 0, 0);
        }
    }
    int rbase = blk*64 + wave*16 + (lane >> 4)*4;
    #pragma unroll
    for(int c=0;c<NT;++c){
        #pragma unroll
        for(int r=0;r<4;++r){
            C[(size_t)(rbase + r)*OUT + c*16 + col16] = f2bf(acc[c][r]);
        }
    }
    if(DOT){
        float pa[4] = {0,0,0,0}, pb[4] = {0,0,0,0};
        #pragma unroll
        for(int c=0;c<NT;++c){
            float a = va[c*16 + col16];
            float b = vb[c*16 + col16];
            #pragma unroll
            for(int r=0;r<4;++r){ pa[r] += acc[c][r]*a; pb[r] += acc[c][r]*b; }
        }
        #pragma unroll
        for(int o=1;o<16;o<<=1){
            #pragma unroll
            for(int r=0;r<4;++r){ pa[r] += __shfl_xor(pa[r], o); pb[r] += __shfl_xor(pb[r], o); }
        }
        if(col16 == 0){
            #pragma unroll
            for(int r=0;r<4;++r){ oa[rbase + r] = pa[r]; ob[rbase + r] = pb[r]; }
        }
    }
}

// ---------------- B1 GEMM with 16 extra weight columns = fused es8/ed8 ----------------
__global__ __launch_bounds__(256) void k_gemm_b1(const ushort_t* __restrict__ A,
                                                 const float* __restrict__ W,
                                                 const float* __restrict__ asrc,
                                                 const float* __restrict__ adst,
                                                 ushort_t* __restrict__ C,
                                                 float* __restrict__ es8,
                                                 float* __restrict__ ed8){
    constexpr int IN = HID, OUTW = D160, NT = 11, KS = IN/32, LDW = IN + 8;
    __shared__ __align__(16) ushort_t Wt[(OUTW+16)*LDW];
    int tid = threadIdx.x;
    for(int i = tid; i < IN*OUTW; i += 256){
        int k = i / OUTW, n = i - k*OUTW;
        Wt[n*LDW + k] = f2bf(W[i]);
    }
    for(int i = tid; i < IN*16; i += 256){
        int k = i >> 4, j = i & 15;
        const float* av = (j < 8 ? asrc : adst) + (j & 7)*F1;
        const float* wr = W + k*OUTW + (j & 7)*F1;
        float s = 0.f;
        #pragma unroll
        for(int f=0; f<F1; ++f) s += wr[f]*av[f];
        Wt[(OUTW + j)*LDW + k] = f2bf(s);
    }
    __syncthreads();
    int blk = xswz(blockIdx.x, N_NODES/64);
    int wave = tid >> 6, lane = tid & 63;
    int col16 = lane & 15;
    int kq = (lane >> 4) * 8;
    int row = blk*64 + wave*16 + col16;
    const ushort_t* Ar = A + (size_t)row*IN + kq;
    f32x4 acc[NT];
    #pragma unroll
    for(int c=0;c<NT;++c) acc[c] = (f32x4){0.f,0.f,0.f,0.f};
    #pragma unroll
    for(int ks=0; ks<KS; ++ks){
        short8 af = *reinterpret_cast<const short8*>(Ar + ks*32);
        #pragma unroll
        for(int c=0;c<NT;++c){
            short8 bf = *reinterpret_cast<const short8*>(&Wt[(c*16 + col16)*LDW + ks*32 + kq]);
            acc[c] = __builtin_amdgcn_mfma_f32_16x16x32_bf16(af, bf, acc[c], 0, 0, 0);
        }
    }
    int rbase = blk*64 + wave*16 + (lane >> 4)*4;
    #pragma unroll
    for(int c=0;c<10;++c){
        #pragma unroll
        for(int r=0;r<4;++r){
            C[(size_t)(rbase + r)*OUTW + c*16 + col16] = f2bf(acc[c][r]);
        }
    }
    #pragma unroll
    for(int r=0;r<4;++r){
        float v = acc[10][r];
        if(col16 < 8) es8[(size_t)(rbase + r)*8 + col16] = v;
        else          ed8[(size_t)(rbase + r)*8 + (col16 - 8)] = v;
    }
}

// ---------------- 1-head attention aggregate (wave per node), bf16 Z ----------------
template<typename OutT, bool DOT>
__global__ void k_attn1(const int* __restrict__ deg, const int* __restrict__ ell,
                        const ushort_t* __restrict__ Z, const float* __restrict__ es,
                        const float* __restrict__ ed, const float* __restrict__ bias,
                        OutT* __restrict__ out,
                        const float* __restrict__ wa, const float* __restrict__ wb,
                        float* __restrict__ oa, float* __restrict__ ob){
    int blk = xswz(blockIdx.x, N_NODES/4);
    int gt = blk*blockDim.x + threadIdx.x;
    int n = gt >> 6;
    int l = threadIdx.x & 63;
    int dg = deg[n]; if(dg > MAXDEG) dg = MAXDEG;
    float edn = ed[n];
    float eself = lrelu(es[n] + edn);
    int s_l = 0; float e_l = -1e30f;
    if(l < dg){ s_l = ell[n*MAXDEG + l]; e_l = lrelu(es[s_l] + edn); }
    float m = fmaxf(e_l, eself);
    for(int o=32;o>0;o>>=1) m = fmaxf(m, __shfl_xor(m,o));
    float w_l = (l < dg) ? expf(e_l - m) : 0.f;
    float den = w_l;
    for(int o=32;o>0;o>>=1) den += __shfl_xor(den,o);
    float wself = expf(eself - m);
    den += wself;
    const uint_t* Zu = (const uint_t*)Z;
    uint_t zn = Zu[(size_t)n*64 + l];
    float acc0 = wself*bflo(zn);
    float acc1 = wself*bfhi(zn);
    int i = 0;
    for(; i+4 <= dg; i += 4){
        int s0 = __builtin_amdgcn_readlane(s_l, i);
        int s1 = __builtin_amdgcn_readlane(s_l, i+1);
        int s2 = __builtin_amdgcn_readlane(s_l, i+2);
        int s3 = __builtin_amdgcn_readlane(s_l, i+3);
        uint_t z0 = Zu[(size_t)s0*64 + l];
        uint_t z1 = Zu[(size_t)s1*64 + l];
        uint_t z2 = Zu[(size_t)s2*64 + l];
        uint_t z3 = Zu[(size_t)s3*64 + l];
        float w0 = rdlanef(w_l, i);
        float w1 = rdlanef(w_l, i+1);
        float w2 = rdlanef(w_l, i+2);
        float w3 = rdlanef(w_l, i+3);
        acc0 += w0*bflo(z0) + w1*bflo(z1);
        acc1 += w0*bfhi(z0) + w1*bfhi(z1);
        acc0 += w2*bflo(z2) + w3*bflo(z3);
        acc1 += w2*bfhi(z2) + w3*bfhi(z3);
    }
    for(; i < dg; ++i){
        int s0 = __builtin_amdgcn_readlane(s_l, i);
        float w0 = rdlanef(w_l, i);
        uint_t z0 = Zu[(size_t)s0*64 + l];
        acc0 += w0*bflo(z0);
        acc1 += w0*bfhi(z0);
    }
    float inv = 1.f/(den + 1e-16f);
    float2 bb = ((const float2*)bias)[l];
    float r0 = fmaxf(acc0*inv + bb.x, 0.f);
    float r1 = fmaxf(acc1*inv + bb.y, 0.f);
    if(sizeof(OutT) == 2){
        ((uint_t*)out)[(size_t)n*64 + l] = (uint_t)f2bf(r0) | ((uint_t)f2bf(r1) << 16);
    } else {
        float2 rv; rv.x = r0; rv.y = r1;
        ((float2*)out)[(size_t)n*64 + l] = rv;
    }
    if(DOT){
        float2 a2 = ((const float2*)wa)[l];
        float2 b2 = ((const float2*)wb)[l];
        float pa = r0*a2.x + r1*a2.y;
        float pb = r0*b2.x + r1*b2.y;
        for(int o=32;o>0;o>>=1){ pa += __shfl_xor(pa,o); pb += __shfl_xor(pb,o); }
        if(l==0){ oa[n] = pa; ob[n] = pb; }
    }
}

// ---------------- pooling score ----------------
__global__ void k_score(const int* __restrict__ deg, const int* __restrict__ ell,
                        const float* __restrict__ yrel, const float* __restrict__ rroot,
                        const float* __restrict__ bpool, float* __restrict__ score){
    int blk = xswz(blockIdx.x, N_NODES/256);
    int n = blk*blockDim.x + threadIdx.x;
    int dg = deg[n]; if(dg > MAXDEG) dg = MAXDEG;
    float s = rroot[n] + bpool[0];
    const int* el = ell + n*MAXDEG;
    int i = 0;
    for(; i+4 <= dg; i += 4){
        float y0 = yrel[el[i]],   y1 = yrel[el[i+1]];
        float y2 = yrel[el[i+2]], y3 = yrel[el[i+3]];
        s += (y0 + y1) + (y2 + y3);
    }
    for(; i < dg; ++i) s += yrel[el[i]];
    score[n] = tanhf(s);
}

// ---------------- per-graph top-k: single-wave register bitonic + parallel pool ----------------
__global__ __launch_bounds__(512) void k_topk_pool(const float* __restrict__ score,
                                                   const float* __restrict__ H,
                                                   float* __restrict__ pooled,
                                                   float* __restrict__ perm_f,
                                                   float* __restrict__ sv,
                                                   float* __restrict__ batch_f){
    __shared__ int   sidx[KSEL];
    __shared__ float sval[KSEL];
    __shared__ float pmax[512];
    int g = xswz(blockIdx.x, NGRAPH);
    int base = g*NPG;
    int t = threadIdx.x;
    if(t < 64){
        int l = t;
        u64 v[8];
        #pragma unroll
        for(int r=0;r<8;++r){
            int i = r*64 + l;
            v[r] = comp_make(score[base + i], i);
        }
        #pragma unroll
        for(int kk=1; kk<=9; ++kk){
            int k = 1 << kk;
            #pragma unroll
            for(int jj=kk-1; jj>=0; --jj){
                int j = 1 << jj;
                if(j < 64){
                    bool lower = (l & j) == 0;
                    #pragma unroll
                    for(int r=0;r<8;++r){
                        int i = r*64 + l;
                        u64 p = shfl_xor_u64(v[r], j);
                        bool desc = (i & k) == 0;
                        u64 mx = v[r] > p ? v[r] : p;
                        u64 mn = v[r] > p ? p : v[r];
                        v[r] = (lower == desc) ? mx : mn;
                    }
                } else {
                    int jr = j >> 6;
                    #pragma unroll
                    for(int r=0;r<8;++r){
                        if((r & jr) == 0){
                            int rp = r | jr;
                            int i = r*64 + l;
                            bool desc = (i & k) == 0;
                            u64 a = v[r], b = v[rp];
                            u64 mx = a > b ? a : b;
                            u64 mn = a > b ? b : a;
                            v[r]  = desc ? mx : mn;
                            v[rp] = desc ? mn : mx;
                        }
                    }
                }
            }
        }
        #pragma unroll
        for(int r=0;r<4;++r){
            int i = r*64 + l;
            int idx = comp_idx(v[r]);
            float s = comp_score(v[r]);
            perm_f[g*KSEL + i]  = (float)(base + idx);
            sv[g*KSEL + i]      = s;
            batch_f[g*KSEL + i] = (float)g;
            sidx[i] = idx; sval[i] = s;
        }
    }
    __syncthreads();
    int c = t & 127, kc = t >> 7;
    float mx = -1e30f;
    for(int kk = kc*64; kk < kc*64 + 64; ++kk){
        mx = fmaxf(mx, H[(size_t)(base + sidx[kk])*HID + c] * sval[kk]);
    }
    pmax[t] = mx;
    __syncthreads();
    if(t < HID){
        pooled[g*HID + t] = fmaxf(fmaxf(pmax[t], pmax[t+128]),
                                  fmaxf(pmax[t+256], pmax[t+384]));
    }
}

extern "C" void kernel_launch(void* const* d_in, const int* in_sizes, int n_in,
                              void* d_out, int out_size, void* d_ws, size_t ws_size,
                              hipStream_t stream) {
    const int*   x       = (const int*)  d_in[0];
    const int*   eidx    = (const int*)  d_in[1];
    const float* W_a1    = (const float*)d_in[3];
    const float* asrc_a1 = (const float*)d_in[4];
    const float* adst_a1 = (const float*)d_in[5];
    const float* b_a1    = (const float*)d_in[6];
    const float* W_a2    = (const float*)d_in[7];
    const float* asrc_a2 = (const float*)d_in[8];
    const float* adst_a2 = (const float*)d_in[9];
    const float* b_a2    = (const float*)d_in[10];
    const float* W_b1    = (const float*)d_in[11];
    const float* asrc_b1 = (const float*)d_in[12];
    const float* adst_b1 = (const float*)d_in[13];
    const float* b_b1    = (const float*)d_in[14];
    const float* W_b2    = (const float*)d_in[15];
    const float* asrc_b2 = (const float*)d_in[16];
    const float* adst_b2 = (const float*)d_in[17];
    const float* b_b2    = (const float*)d_in[18];
    const float* w_rel   = (const float*)d_in[19];
    const float* w_root  = (const float*)d_in[20];
    const float* b_pool  = (const float*)d_in[21];

    const int* e_src = eidx;
    const int* e_dst = eidx + E_EDGES;

    char* ws = (char*)d_ws;
    size_t off = 0;
    auto alloc = [&](size_t bytes)->char*{
        char* p = ws + off;
        off += (bytes + 255) & ~(size_t)255;
        return p;
    };
    int*      deg   = (int*)     alloc((size_t)N_NODES*4);
    int*      ell   = (int*)     alloc((size_t)N_NODES*MAXDEG*4);
    ushort_t* z8    = (ushort_t*)alloc((size_t)N_NODES*D160*2);
    ushort_t* h8    = (ushort_t*)alloc((size_t)N_NODES*D160*2);
    ushort_t* zc    = (ushort_t*)alloc((size_t)N_NODES*HID*2);
    ushort_t* hmid  = (ushort_t*)alloc((size_t)N_NODES*HID*2);
    float*    hfin  = (float*)   alloc((size_t)N_NODES*HID*4);
    float*    es8   = (float*)   alloc((size_t)N_NODES*NHEADS*4);
    float*    ed8   = (float*)   alloc((size_t)N_NODES*NHEADS*4);
    float*    es1   = (float*)   alloc((size_t)N_NODES*4);
    float*    ed1   = (float*)   alloc((size_t)N_NODES*4);
    float*    yrel  = (float*)   alloc((size_t)N_NODES*4);
    float*    rroot = (float*)   alloc((size_t)N_NODES*4);
    float*    score = (float*)   alloc((size_t)N_NODES*4);
    (void)ws_size; (void)n_in; (void)in_sizes; (void)out_size;

    float* out      = (float*)d_out;
    float* pooled   = out;
    float* perm_f   = out + NGRAPH*HID;
    float* sv       = perm_f + NGRAPH*KSEL;
    float* batch_f  = sv + NGRAPH*KSEL;

    // zero deg with our own kernel (rocclr fillBuffer takes ~43us for 256KB)
    k_zero<<<N_NODES*4/(16*256), 256, 0, stream>>>((uint4*)deg);
    k_build_ell<<<E_EDGES/256, 256, 0, stream>>>(e_src, e_dst, deg, ell);

    // ---- GATNet A, conv1 (one-hot gather -> 20x8) ----
    k_a1_z<<<N_NODES*NHEADS/256, 256, 0, stream>>>(x, W_a1, asrc_a1, adst_a1, z8, es8, ed8);
    k_attn8<<<N_NODES*NHEADS/256, 256, 0, stream>>>(deg, ell, z8, es8, ed8, b_a1, h8);

    // ---- GATNet A, conv2 (160 -> 128) + fused es/ed dots ----
    k_gemm_mfma<D160, HID, true><<<N_NODES/64, 256, 0, stream>>>(h8, W_a2, zc, asrc_a2, adst_a2, es1, ed1);
    k_attn1<ushort_t, false><<<N_NODES/4, 256, 0, stream>>>(deg, ell, zc, es1, ed1, b_a2, hmid,
                                                            nullptr, nullptr, nullptr, nullptr);

    // ---- GATNet B, conv1 (128 -> 20x8) + fused es8/ed8 via extended weight ----
    k_gemm_b1<<<N_NODES/64, 256, 0, stream>>>(hmid, W_b1, asrc_b1, adst_b1, z8, es8, ed8);
    k_attn8<<<N_NODES*NHEADS/256, 256, 0, stream>>>(deg, ell, z8, es8, ed8, b_b1, h8);

    // ---- GATNet B, conv2 (160 -> 128) + fused es/ed dots ----
    k_gemm_mfma<D160, HID, true><<<N_NODES/64, 256, 0, stream>>>(h8, W_b2, zc, asrc_b2, adst_b2, es1, ed1);
    // final attention + fused pooling dots (yrel, rroot)
    k_attn1<float, true><<<N_NODES/4, 256, 0, stream>>>(deg, ell, zc, es1, ed1, b_b2, hfin,
                                                        w_rel, w_root, yrel, rroot);

    // ---- SAGPooling ----
    k_score<<<N_NODES/256, 256, 0, stream>>>(deg, ell, yrel, rroot, b_pool, score);
    k_topk_pool<<<NGRAPH, NPG, 0, stream>>>(score, hfin, pooled, perm_f, sv, batch_f);
}

// Round 8
// 240.476 us; speedup vs baseline: 1.0988x; 1.0672x over previous
//
#include <hip/hip_runtime.h>
#include <math.h>

#define N_NODES 65536
#define NPG     512
#define NGRAPH  128
#define E_EDGES 524288
#define MAXDEG  64
#define NHEADS  8
#define F1      20
#define HID     128
#define D160    160
#define KSEL    256
#define NLBL    100

typedef unsigned short ushort_t;
typedef unsigned int   uint_t;
typedef unsigned long long u64;
typedef __attribute__((ext_vector_type(8))) short short8;
typedef __attribute__((ext_vector_type(4))) float f32x4;

__device__ __forceinline__ float lrelu(float x){ return x > 0.f ? x : 0.2f*x; }
__device__ __forceinline__ ushort_t f2bf(float f){
    uint_t u = __float_as_uint(f);
    return (ushort_t)((u + 0x7FFFu + ((u >> 16) & 1u)) >> 16);
}
__device__ __forceinline__ float bf2f(ushort_t u){ return __uint_as_float(((uint_t)u) << 16); }
__device__ __forceinline__ float bflo(uint_t v){ return __uint_as_float(v << 16); }
__device__ __forceinline__ float bfhi(uint_t v){ return __uint_as_float(v & 0xFFFF0000u); }
// XCD-coherent block swizzle: graph tiles pinned to one XCD across ALL kernels.
__device__ __forceinline__ int xswz(int bid, int nblocks){
    return (bid & 7) * (nblocks >> 3) + (bid >> 3);
}
__device__ __forceinline__ float rdlanef(float v, int i){
    return __uint_as_float((uint_t)__builtin_amdgcn_readlane(__float_as_int(v), i));
}

// sortable composite: desc score, tie -> asc idx
__device__ __forceinline__ u64 comp_make(float s, int idx){
    uint_t u = __float_as_uint(s);
    u ^= (u & 0x80000000u) ? 0xFFFFFFFFu : 0x80000000u;
    return ((u64)u << 32) | (u64)(511 - idx);
}
__device__ __forceinline__ float comp_score(u64 c){
    uint_t u = (uint_t)(c >> 32);
    u ^= (u & 0x80000000u) ? 0x80000000u : 0xFFFFFFFFu;
    return __uint_as_float(u);
}
__device__ __forceinline__ int comp_idx(u64 c){ return 511 - (int)(c & 0x1FFu); }
__device__ __forceinline__ u64 shfl_xor_u64(u64 x, int m){
    uint_t lo = __shfl_xor((uint_t)x, m);
    uint_t hi = __shfl_xor((uint_t)(x >> 32), m);
    return ((u64)hi << 32) | lo;
}

// ---------------- fast zero ----------------
__global__ void k_zero(uint4* __restrict__ p){
    p[blockIdx.x*blockDim.x + threadIdx.x] = (uint4){0,0,0,0};
}

// ---------------- ELL adjacency build (dst -> list of src) ----------------
__global__ void k_build_ell(const int* __restrict__ src, const int* __restrict__ dst,
                            int* __restrict__ deg, int* __restrict__ ell){
    int blk = xswz(blockIdx.x, E_EDGES/256);
    int e = blk*blockDim.x + threadIdx.x;
    int d = dst[e];
    int p = atomicAdd(&deg[d], 1);
    if(p < MAXDEG) ell[d*MAXDEG + p] = src[e];
}

// ---------------- layer A prep: bf16 W table + per-label es/ed tables ----------------
__global__ void k_prep_a(const float* __restrict__ W, const float* __restrict__ asrc,
                         const float* __restrict__ adst,
                         ushort_t* __restrict__ Wbf, float* __restrict__ esT,
                         float* __restrict__ edT){
    int lbl = blockIdx.x;          // NLBL blocks
    int f = threadIdx.x;           // D160 threads
    const float* wrow = W + lbl*D160;
    Wbf[lbl*D160 + f] = f2bf(wrow[f]);
    if(f < 16){
        int h = f & 7;
        const float* av = ((f < 8) ? asrc : adst) + h*F1;
        float s = 0.f;
        #pragma unroll
        for(int k=0; k<F1; ++k) s += wrow[h*F1 + k]*av[k];
        if(f < 8) esT[lbl*8 + h] = s;
        else      edT[lbl*8 + h] = s;
    }
}

// ---------------- layer A fused z-gen + 8-head attention (LDS table; no-max softmax) ----
__global__ __launch_bounds__(256) void k_attn8_a(const int* __restrict__ x,
        const int* __restrict__ deg, const int* __restrict__ ell,
        const ushort_t* __restrict__ Wbf, const float* __restrict__ esT,
        const float* __restrict__ edT, const float* __restrict__ bias,
        ushort_t* __restrict__ out){
    __shared__ __align__(16) ushort_t Wl[NLBL*D160];   // 32000 B
    __shared__ float esL[NLBL*8], edL[NLBL*8];         // 2x3200 B
    int tid = threadIdx.x;
    for(int i = tid; i < NLBL*D160/8; i += 256)
        ((uint4*)Wl)[i] = ((const uint4*)Wbf)[i];
    for(int i = tid; i < NLBL*8; i += 256){ esL[i] = esT[i]; edL[i] = edT[i]; }
    __syncthreads();
    int blk = xswz(blockIdx.x, N_NODES*NHEADS/256);
    int t = blk*256 + tid;
    int n = t >> 3, h = t & 7;
    int dg = deg[n]; if(dg > MAXDEG) dg = MAXDEG;
    int lbl = x[n];
    float edn = edL[lbl*8 + h];
    float wself = expf(lrelu(esL[lbl*8 + h] + edn));
    float den = wself;
    float acc[F1];
    {
        const uint_t* zn = (const uint_t*)Wl + lbl*80 + h*10;
        #pragma unroll
        for(int f=0; f<10; ++f){
            uint_t v = zn[f];
            acc[2*f]   = wself*bflo(v);
            acc[2*f+1] = wself*bfhi(v);
        }
    }
    const int* el = ell + n*MAXDEG;
    int i = 0;
    for(; i+2 <= dg; i += 2){
        int sa = el[i], sb = el[i+1];
        int la = x[sa], lb = x[sb];
        float wa = expf(lrelu(esL[la*8 + h] + edn));
        float wb = expf(lrelu(esL[lb*8 + h] + edn));
        den += wa + wb;
        const uint_t* za = (const uint_t*)Wl + la*80 + h*10;
        const uint_t* zb = (const uint_t*)Wl + lb*80 + h*10;
        #pragma unroll
        for(int f=0; f<10; ++f){
            uint_t va = za[f], vb = zb[f];
            acc[2*f]   += wa*bflo(va) + wb*bflo(vb);
            acc[2*f+1] += wa*bfhi(va) + wb*bfhi(vb);
        }
    }
    if(i < dg){
        int sa = el[i];
        int la = x[sa];
        float wa = expf(lrelu(esL[la*8 + h] + edn));
        den += wa;
        const uint_t* za = (const uint_t*)Wl + la*80 + h*10;
        #pragma unroll
        for(int f=0; f<10; ++f){
            uint_t va = za[f];
            acc[2*f]   += wa*bflo(va);
            acc[2*f+1] += wa*bfhi(va);
        }
    }
    float inv = 1.f/(den + 1e-16f);
    uint_t* o = (uint_t*)(out + (size_t)n*D160 + h*F1);
    const float* bb = bias + h*F1;
    #pragma unroll
    for(int f=0; f<10; ++f){
        float v0 = fmaxf(acc[2*f]*inv   + bb[2*f],   0.f);
        float v1 = fmaxf(acc[2*f+1]*inv + bb[2*f+1], 0.f);
        o[f] = (uint_t)f2bf(v0) | ((uint_t)f2bf(v1) << 16);
    }
}

// ---------------- 8-head attention (layer B): single pass, no-max softmax ----------------
__global__ void k_attn8(const int* __restrict__ deg, const int* __restrict__ ell,
                        const ushort_t* __restrict__ z8, const float* __restrict__ es8,
                        const float* __restrict__ ed8, const float* __restrict__ bias,
                        ushort_t* __restrict__ out){
    int blk = xswz(blockIdx.x, N_NODES*NHEADS/256);
    int t = blk*blockDim.x + threadIdx.x;
    int n = t >> 3, h = t & 7;
    int dg = deg[n]; if(dg > MAXDEG) dg = MAXDEG;
    float edn = ed8[t];
    float wself = expf(lrelu(es8[t] + edn));
    float den = wself;
    float acc[F1];
    const uint_t* zn = (const uint_t*)(z8 + (size_t)n*D160 + h*F1);
    #pragma unroll
    for(int f=0; f<10; ++f){
        uint_t v = zn[f];
        acc[2*f]   = wself*bflo(v);
        acc[2*f+1] = wself*bfhi(v);
    }
    const int* el = ell + n*MAXDEG;
    int i = 0;
    for(; i+2 <= dg; i += 2){
        int sa = el[i], sb = el[i+1];
        float ea = es8[sa*NHEADS + h], eb = es8[sb*NHEADS + h];
        const uint_t* za = (const uint_t*)(z8 + (size_t)sa*D160 + h*F1);
        const uint_t* zb = (const uint_t*)(z8 + (size_t)sb*D160 + h*F1);
        float wa = expf(lrelu(ea + edn));
        float wb = expf(lrelu(eb + edn));
        den += wa + wb;
        #pragma unroll
        for(int f=0; f<10; ++f){
            uint_t va = za[f], vb = zb[f];
            acc[2*f]   += wa*bflo(va) + wb*bflo(vb);
            acc[2*f+1] += wa*bfhi(va) + wb*bfhi(vb);
        }
    }
    if(i < dg){
        int sa = el[i];
        float ea = es8[sa*NHEADS + h];
        const uint_t* za = (const uint_t*)(z8 + (size_t)sa*D160 + h*F1);
        float wa = expf(lrelu(ea + edn));
        den += wa;
        #pragma unroll
        for(int f=0; f<10; ++f){
            uint_t va = za[f];
            acc[2*f]   += wa*bflo(va);
            acc[2*f+1] += wa*bfhi(va);
        }
    }
    float inv = 1.f/(den + 1e-16f);
    uint_t* o = (uint_t*)(out + (size_t)n*D160 + h*F1);
    const float* bb = bias + h*F1;
    #pragma unroll
    for(int f=0; f<10; ++f){
        float v0 = fmaxf(acc[2*f]*inv   + bb[2*f],   0.f);
        float v1 = fmaxf(acc[2*f+1]*inv + bb[2*f+1], 0.f);
        o[f] = (uint_t)f2bf(v0) | ((uint_t)f2bf(v1) << 16);
    }
}

// ---------------- bf16 MFMA GEMM + optional fused row-dot epilogue ----------------
template<int IN, int OUT, bool DOT>
__global__ __launch_bounds__(256) void k_gemm_mfma(const ushort_t* __restrict__ A,
                                                   const float* __restrict__ W,
                                                   ushort_t* __restrict__ C,
                                                   const float* __restrict__ va,
                                                   const float* __restrict__ vb,
                                                   float* __restrict__ oa,
                                                   float* __restrict__ ob){
    constexpr int NT = OUT/16;
    constexpr int KS = IN/32;
    constexpr int LDW = IN + 8;
    __shared__ __align__(16) ushort_t Wt[OUT*LDW];
    int tid = threadIdx.x;
    for(int i = tid; i < IN*OUT; i += 256){
        int k = i / OUT, n = i - k*OUT;
        Wt[n*LDW + k] = f2bf(W[i]);
    }
    __syncthreads();
    int blk = xswz(blockIdx.x, N_NODES/64);
    int wave = tid >> 6, lane = tid & 63;
    int col16 = lane & 15;
    int kq = (lane >> 4) * 8;
    int row = blk*64 + wave*16 + col16;
    const ushort_t* Ar = A + (size_t)row*IN + kq;
    f32x4 acc[NT];
    #pragma unroll
    for(int c=0;c<NT;++c) acc[c] = (f32x4){0.f,0.f,0.f,0.f};
    #pragma unroll
    for(int ks=0; ks<KS; ++ks){
        short8 af = *reinterpret_cast<const short8*>(Ar + ks*32);
        #pragma unroll
        for(int c=0;c<NT;++c){
            short8 bf = *reinterpret_cast<const short8*>(&Wt[(c*16 + col16)*LDW + ks*32 + kq]);
            acc[c] = __builtin_amdgcn_mfma_f32_16x16x32_bf16(af, bf, acc[c], 0, 0, 0);
        }
    }
    int rbase = blk*64 + wave*16 + (lane >> 4)*4;
    #pragma unroll
    for(int c=0;c<NT;++c){
        #pragma unroll
        for(int r=0;r<4;++r){
            C[(size_t)(rbase + r)*OUT + c*16 + col16] = f2bf(acc[c][r]);
        }
    }
    if(DOT){
        float pa[4] = {0,0,0,0}, pb[4] = {0,0,0,0};
        #pragma unroll
        for(int c=0;c<NT;++c){
            float a = va[c*16 + col16];
            float b = vb[c*16 + col16];
            #pragma unroll
            for(int r=0;r<4;++r){ pa[r] += acc[c][r]*a; pb[r] += acc[c][r]*b; }
        }
        #pragma unroll
        for(int o=1;o<16;o<<=1){
            #pragma unroll
            for(int r=0;r<4;++r){ pa[r] += __shfl_xor(pa[r], o); pb[r] += __shfl_xor(pb[r], o); }
        }
        if(col16 == 0){
            #pragma unroll
            for(int r=0;r<4;++r){ oa[rbase + r] = pa[r]; ob[rbase + r] = pb[r]; }
        }
    }
}

// ---------------- B1 GEMM with 16 extra weight columns = fused es8/ed8 ----------------
__global__ __launch_bounds__(256) void k_gemm_b1(const ushort_t* __restrict__ A,
                                                 const float* __restrict__ W,
                                                 const float* __restrict__ asrc,
                                                 const float* __restrict__ adst,
                                                 ushort_t* __restrict__ C,
                                                 float* __restrict__ es8,
                                                 float* __restrict__ ed8){
    constexpr int IN = HID, OUTW = D160, NT = 11, KS = IN/32, LDW = IN + 8;
    __shared__ __align__(16) ushort_t Wt[(OUTW+16)*LDW];
    int tid = threadIdx.x;
    for(int i = tid; i < IN*OUTW; i += 256){
        int k = i / OUTW, n = i - k*OUTW;
        Wt[n*LDW + k] = f2bf(W[i]);
    }
    for(int i = tid; i < IN*16; i += 256){
        int k = i >> 4, j = i & 15;
        const float* av = (j < 8 ? asrc : adst) + (j & 7)*F1;
        const float* wr = W + k*OUTW + (j & 7)*F1;
        float s = 0.f;
        #pragma unroll
        for(int f=0; f<F1; ++f) s += wr[f]*av[f];
        Wt[(OUTW + j)*LDW + k] = f2bf(s);
    }
    __syncthreads();
    int blk = xswz(blockIdx.x, N_NODES/64);
    int wave = tid >> 6, lane = tid & 63;
    int col16 = lane & 15;
    int kq = (lane >> 4) * 8;
    int row = blk*64 + wave*16 + col16;
    const ushort_t* Ar = A + (size_t)row*IN + kq;
    f32x4 acc[NT];
    #pragma unroll
    for(int c=0;c<NT;++c) acc[c] = (f32x4){0.f,0.f,0.f,0.f};
    #pragma unroll
    for(int ks=0; ks<KS; ++ks){
        short8 af = *reinterpret_cast<const short8*>(Ar + ks*32);
        #pragma unroll
        for(int c=0;c<NT;++c){
            short8 bf = *reinterpret_cast<const short8*>(&Wt[(c*16 + col16)*LDW + ks*32 + kq]);
            acc[c] = __builtin_amdgcn_mfma_f32_16x16x32_bf16(af, bf, acc[c], 0, 0, 0);
        }
    }
    int rbase = blk*64 + wave*16 + (lane >> 4)*4;
    #pragma unroll
    for(int c=0;c<10;++c){
        #pragma unroll
        for(int r=0;r<4;++r){
            C[(size_t)(rbase + r)*OUTW + c*16 + col16] = f2bf(acc[c][r]);
        }
    }
    #pragma unroll
    for(int r=0;r<4;++r){
        float v = acc[10][r];
        if(col16 < 8) es8[(size_t)(rbase + r)*8 + col16] = v;
        else          ed8[(size_t)(rbase + r)*8 + (col16 - 8)] = v;
    }
}

// ---------------- 1-head attention aggregate (wave per node), no-max softmax ----------------
template<typename OutT, bool DOT>
__global__ void k_attn1(const int* __restrict__ deg, const int* __restrict__ ell,
                        const ushort_t* __restrict__ Z, const float* __restrict__ es,
                        const float* __restrict__ ed, const float* __restrict__ bias,
                        OutT* __restrict__ out,
                        const float* __restrict__ wa, const float* __restrict__ wb,
                        float* __restrict__ oa, float* __restrict__ ob){
    int blk = xswz(blockIdx.x, N_NODES/4);
    int gt = blk*blockDim.x + threadIdx.x;
    int n = gt >> 6;
    int l = threadIdx.x & 63;
    int dg = deg[n]; if(dg > MAXDEG) dg = MAXDEG;
    float edn = ed[n];
    float wself = expf(lrelu(es[n] + edn));
    int s_l = 0; float w_l = 0.f;
    if(l < dg){ s_l = ell[n*MAXDEG + l]; w_l = expf(lrelu(es[s_l] + edn)); }
    float den = w_l;
    for(int o=32;o>0;o>>=1) den += __shfl_xor(den,o);
    den += wself;
    const uint_t* Zu = (const uint_t*)Z;
    uint_t zn = Zu[(size_t)n*64 + l];
    float acc0 = wself*bflo(zn);
    float acc1 = wself*bfhi(zn);
    int i = 0;
    for(; i+4 <= dg; i += 4){
        int s0 = __builtin_amdgcn_readlane(s_l, i);
        int s1 = __builtin_amdgcn_readlane(s_l, i+1);
        int s2 = __builtin_amdgcn_readlane(s_l, i+2);
        int s3 = __builtin_amdgcn_readlane(s_l, i+3);
        uint_t z0 = Zu[(size_t)s0*64 + l];
        uint_t z1 = Zu[(size_t)s1*64 + l];
        uint_t z2 = Zu[(size_t)s2*64 + l];
        uint_t z3 = Zu[(size_t)s3*64 + l];
        float w0 = rdlanef(w_l, i);
        float w1 = rdlanef(w_l, i+1);
        float w2 = rdlanef(w_l, i+2);
        float w3 = rdlanef(w_l, i+3);
        acc0 += w0*bflo(z0) + w1*bflo(z1);
        acc1 += w0*bfhi(z0) + w1*bfhi(z1);
        acc0 += w2*bflo(z2) + w3*bflo(z3);
        acc1 += w2*bfhi(z2) + w3*bfhi(z3);
    }
    for(; i < dg; ++i){
        int s0 = __builtin_amdgcn_readlane(s_l, i);
        float w0 = rdlanef(w_l, i);
        uint_t z0 = Zu[(size_t)s0*64 + l];
        acc0 += w0*bflo(z0);
        acc1 += w0*bfhi(z0);
    }
    float inv = 1.f/(den + 1e-16f);
    float2 bb = ((const float2*)bias)[l];
    float r0 = fmaxf(acc0*inv + bb.x, 0.f);
    float r1 = fmaxf(acc1*inv + bb.y, 0.f);
    if(sizeof(OutT) == 2){
        ((uint_t*)out)[(size_t)n*64 + l] = (uint_t)f2bf(r0) | ((uint_t)f2bf(r1) << 16);
    } else {
        float2 rv; rv.x = r0; rv.y = r1;
        ((float2*)out)[(size_t)n*64 + l] = rv;
    }
    if(DOT){
        float2 a2 = ((const float2*)wa)[l];
        float2 b2 = ((const float2*)wb)[l];
        float pa = r0*a2.x + r1*a2.y;
        float pb = r0*b2.x + r1*b2.y;
        for(int o=32;o>0;o>>=1){ pa += __shfl_xor(pa,o); pb += __shfl_xor(pb,o); }
        if(l==0){ oa[n] = pa; ob[n] = pb; }
    }
}

// ---------------- pooling score ----------------
__global__ void k_score(const int* __restrict__ deg, const int* __restrict__ ell,
                        const float* __restrict__ yrel, const float* __restrict__ rroot,
                        const float* __restrict__ bpool, float* __restrict__ score){
    int blk = xswz(blockIdx.x, N_NODES/256);
    int n = blk*blockDim.x + threadIdx.x;
    int dg = deg[n]; if(dg > MAXDEG) dg = MAXDEG;
    float s = rroot[n] + bpool[0];
    const int* el = ell + n*MAXDEG;
    int i = 0;
    for(; i+4 <= dg; i += 4){
        float y0 = yrel[el[i]],   y1 = yrel[el[i+1]];
        float y2 = yrel[el[i+2]], y3 = yrel[el[i+3]];
        s += (y0 + y1) + (y2 + y3);
    }
    for(; i < dg; ++i) s += yrel[el[i]];
    score[n] = tanhf(s);
}

// ---------------- per-graph top-k: single-wave register bitonic + parallel pool ----------------
__global__ __launch_bounds__(512) void k_topk_pool(const float* __restrict__ score,
                                                   const ushort_t* __restrict__ H,
                                                   float* __restrict__ pooled,
                                                   float* __restrict__ perm_f,
                                                   float* __restrict__ sv,
                                                   float* __restrict__ batch_f){
    __shared__ int   sidx[KSEL];
    __shared__ float sval[KSEL];
    __shared__ float pmax[512];
    int g = xswz(blockIdx.x, NGRAPH);
    int base = g*NPG;
    int t = threadIdx.x;
    if(t < 64){
        int l = t;
        u64 v[8];
        #pragma unroll
        for(int r=0;r<8;++r){
            int i = r*64 + l;
            v[r] = comp_make(score[base + i], i);
        }
        #pragma unroll
        for(int kk=1; kk<=9; ++kk){
            int k = 1 << kk;
            #pragma unroll
            for(int jj=kk-1; jj>=0; --jj){
                int j = 1 << jj;
                if(j < 64){
                    bool lower = (l & j) == 0;
                    #pragma unroll
                    for(int r=0;r<8;++r){
                        int i = r*64 + l;
                        u64 p = shfl_xor_u64(v[r], j);
                        bool desc = (i & k) == 0;
                        u64 mx = v[r] > p ? v[r] : p;
                        u64 mn = v[r] > p ? p : v[r];
                        v[r] = (lower == desc) ? mx : mn;
                    }
                } else {
                    int jr = j >> 6;
                    #pragma unroll
                    for(int r=0;r<8;++r){
                        if((r & jr) == 0){
                            int rp = r | jr;
                            int i = r*64 + l;
                            bool desc = (i & k) == 0;
                            u64 a = v[r], b = v[rp];
                            u64 mx = a > b ? a : b;
                            u64 mn = a > b ? b : a;
                            v[r]  = desc ? mx : mn;
                            v[rp] = desc ? mn : mx;
                        }
                    }
                }
            }
        }
        #pragma unroll
        for(int r=0;r<4;++r){
            int i = r*64 + l;
            int idx = comp_idx(v[r]);
            float s = comp_score(v[r]);
            perm_f[g*KSEL + i]  = (float)(base + idx);
            sv[g*KSEL + i]      = s;
            batch_f[g*KSEL + i] = (float)g;
            sidx[i] = idx; sval[i] = s;
        }
    }
    __syncthreads();
    int c = t & 127, kc = t >> 7;
    float mx = -1e30f;
    for(int kk = kc*64; kk < kc*64 + 64; ++kk){
        mx = fmaxf(mx, bf2f(H[(size_t)(base + sidx[kk])*HID + c]) * sval[kk]);
    }
    pmax[t] = mx;
    __syncthreads();
    if(t < HID){
        pooled[g*HID + t] = fmaxf(fmaxf(pmax[t], pmax[t+128]),
                                  fmaxf(pmax[t+256], pmax[t+384]));
    }
}

extern "C" void kernel_launch(void* const* d_in, const int* in_sizes, int n_in,
                              void* d_out, int out_size, void* d_ws, size_t ws_size,
                              hipStream_t stream) {
    const int*   x       = (const int*)  d_in[0];
    const int*   eidx    = (const int*)  d_in[1];
    const float* W_a1    = (const float*)d_in[3];
    const float* asrc_a1 = (const float*)d_in[4];
    const float* adst_a1 = (const float*)d_in[5];
    const float* b_a1    = (const float*)d_in[6];
    const float* W_a2    = (const float*)d_in[7];
    const float* asrc_a2 = (const float*)d_in[8];
    const float* adst_a2 = (const float*)d_in[9];
    const float* b_a2    = (const float*)d_in[10];
    const float* W_b1    = (const float*)d_in[11];
    const float* asrc_b1 = (const float*)d_in[12];
    const float* adst_b1 = (const float*)d_in[13];
    const float* b_b1    = (const float*)d_in[14];
    const float* W_b2    = (const float*)d_in[15];
    const float* asrc_b2 = (const float*)d_in[16];
    const float* adst_b2 = (const float*)d_in[17];
    const float* b_b2    = (const float*)d_in[18];
    const float* w_rel   = (const float*)d_in[19];
    const float* w_root  = (const float*)d_in[20];
    const float* b_pool  = (const float*)d_in[21];

    const int* e_src = eidx;
    const int* e_dst = eidx + E_EDGES;

    char* ws = (char*)d_ws;
    size_t off = 0;
    auto alloc = [&](size_t bytes)->char*{
        char* p = ws + off;
        off += (bytes + 255) & ~(size_t)255;
        return p;
    };
    int*      deg   = (int*)     alloc((size_t)N_NODES*4);
    int*      ell   = (int*)     alloc((size_t)N_NODES*MAXDEG*4);
    ushort_t* z8    = (ushort_t*)alloc((size_t)N_NODES*D160*2);
    ushort_t* h8    = (ushort_t*)alloc((size_t)N_NODES*D160*2);
    ushort_t* zc    = (ushort_t*)alloc((size_t)N_NODES*HID*2);
    ushort_t* hmid  = (ushort_t*)alloc((size_t)N_NODES*HID*2);
    ushort_t* hfin  = (ushort_t*)alloc((size_t)N_NODES*HID*2);
    float*    es8   = (float*)   alloc((size_t)N_NODES*NHEADS*4);
    float*    ed8   = (float*)   alloc((size_t)N_NODES*NHEADS*4);
    float*    es1   = (float*)   alloc((size_t)N_NODES*4);
    float*    ed1   = (float*)   alloc((size_t)N_NODES*4);
    float*    yrel  = (float*)   alloc((size_t)N_NODES*4);
    float*    rroot = (float*)   alloc((size_t)N_NODES*4);
    float*    score = (float*)   alloc((size_t)N_NODES*4);
    ushort_t* Wbf   = (ushort_t*)alloc((size_t)NLBL*D160*2);
    float*    esT   = (float*)   alloc((size_t)NLBL*8*4);
    float*    edT   = (float*)   alloc((size_t)NLBL*8*4);
    (void)ws_size; (void)n_in; (void)in_sizes; (void)out_size;

    float* out      = (float*)d_out;
    float* pooled   = out;
    float* perm_f   = out + NGRAPH*HID;
    float* sv       = perm_f + NGRAPH*KSEL;
    float* batch_f  = sv + NGRAPH*KSEL;

    k_zero<<<N_NODES*4/(16*256), 256, 0, stream>>>((uint4*)deg);
    k_build_ell<<<E_EDGES/256, 256, 0, stream>>>(e_src, e_dst, deg, ell);

    // ---- GATNet A, conv1: label tables + fused table-attention ----
    k_prep_a<<<NLBL, D160, 0, stream>>>(W_a1, asrc_a1, adst_a1, Wbf, esT, edT);
    k_attn8_a<<<N_NODES*NHEADS/256, 256, 0, stream>>>(x, deg, ell, Wbf, esT, edT, b_a1, h8);

    // ---- GATNet A, conv2 (160 -> 128) + fused es/ed dots ----
    k_gemm_mfma<D160, HID, true><<<N_NODES/64, 256, 0, stream>>>(h8, W_a2, zc, asrc_a2, adst_a2, es1, ed1);
    k_attn1<ushort_t, false><<<N_NODES/4, 256, 0, stream>>>(deg, ell, zc, es1, ed1, b_a2, hmid,
                                                            nullptr, nullptr, nullptr, nullptr);

    // ---- GATNet B, conv1 (128 -> 20x8) + fused es8/ed8 via extended weight ----
    k_gemm_b1<<<N_NODES/64, 256, 0, stream>>>(hmid, W_b1, asrc_b1, adst_b1, z8, es8, ed8);
    k_attn8<<<N_NODES*NHEADS/256, 256, 0, stream>>>(deg, ell, z8, es8, ed8, b_b1, h8);

    // ---- GATNet B, conv2 (160 -> 128) + fused es/ed dots ----
    k_gemm_mfma<D160, HID, true><<<N_NODES/64, 256, 0, stream>>>(h8, W_b2, zc, asrc_b2, adst_b2, es1, ed1);
    // final attention (bf16 out) + fused pooling dots (yrel, rroot)
    k_attn1<ushort_t, true><<<N_NODES/4, 256, 0, stream>>>(deg, ell, zc, es1, ed1, b_b2, hfin,
                                                           w_rel, w_root, yrel, rroot);

    // ---- SAGPooling ----
    k_score<<<N_NODES/256, 256, 0, stream>>>(deg, ell, yrel, rroot, b_pool, score);
    k_topk_pool<<<NGRAPH, NPG, 0, stream>>>(score, hfin, pooled, perm_f, sv, batch_f);
}

// Round 9
// 226.369 us; speedup vs baseline: 1.1673x; 1.0623x over previous
//
#include <hip/hip_runtime.h>
#include <math.h>

#define N_NODES 65536
#define NPG     512
#define NGRAPH  128
#define E_EDGES 524288
#define MAXDEG  64
#define NHEADS  8
#define F1      20
#define HID     128
#define D160    160
#define KSEL    256
#define NLBL    100

// prep-kernel block ranges
#define IMG_A2_ELEMS (144*168)
#define IMG_B1_ELEMS (176*136)
#define PB_ZERO 0
#define PB_A2   64
#define PB_B1   (PB_A2 + 95)
#define PB_B2   (PB_B1 + 94)
#define PB_WA1  (PB_B2 + 95)
#define PB_EST  (PB_WA1 + 63)
#define PB_TOT  (PB_EST + 7)

typedef unsigned short ushort_t;
typedef unsigned int   uint_t;
typedef unsigned long long u64;
typedef __attribute__((ext_vector_type(8))) short short8;
typedef __attribute__((ext_vector_type(4))) float f32x4;

__device__ __forceinline__ float lrelu(float x){ return x > 0.f ? x : 0.2f*x; }
__device__ __forceinline__ ushort_t f2bf(float f){
    uint_t u = __float_as_uint(f);
    return (ushort_t)((u + 0x7FFFu + ((u >> 16) & 1u)) >> 16);
}
__device__ __forceinline__ float bf2f(ushort_t u){ return __uint_as_float(((uint_t)u) << 16); }
__device__ __forceinline__ float bflo(uint_t v){ return __uint_as_float(v << 16); }
__device__ __forceinline__ float bfhi(uint_t v){ return __uint_as_float(v & 0xFFFF0000u); }
__device__ __forceinline__ int xswz(int bid, int nblocks){
    return (bid & 7) * (nblocks >> 3) + (bid >> 3);
}
__device__ __forceinline__ float rdlanef(float v, int i){
    return __uint_as_float((uint_t)__builtin_amdgcn_readlane(__float_as_int(v), i));
}

// sortable composite: desc score, tie -> asc idx
__device__ __forceinline__ u64 comp_make(float s, int idx){
    uint_t u = __float_as_uint(s);
    u ^= (u & 0x80000000u) ? 0xFFFFFFFFu : 0x80000000u;
    return ((u64)u << 32) | (u64)(511 - idx);
}
__device__ __forceinline__ float comp_score(u64 c){
    uint_t u = (uint_t)(c >> 32);
    u ^= (u & 0x80000000u) ? 0x80000000u : 0xFFFFFFFFu;
    return __uint_as_float(u);
}
__device__ __forceinline__ int comp_idx(u64 c){ return 511 - (int)(c & 0x1FFu); }
__device__ __forceinline__ u64 shfl_xor_u64(u64 x, int m){
    uint_t lo = __shfl_xor((uint_t)x, m);
    uint_t hi = __shfl_xor((uint_t)(x >> 32), m);
    return ((u64)hi << 32) | lo;
}

// ---------------- mega-prep: zero deg + 3 GEMM weight images + A1 tables ----------------
// GEMM image layout: Wt[n*LDW + k] bf16, n=out col, k=in dim, LDW=IN+8 (pad 0).
// a2/b2 images (144 x 168): rows 0..127 = W cols; 128=W@asrc; 129=W@adst; 130..143 = 0.
// b1 image (176 x 136): rows 0..159 = W cols; 160..167 = W@asrc[h]; 168..175 = W@adst[h].
__global__ void k_prep(const float* __restrict__ Wa1, const float* __restrict__ as1,
                       const float* __restrict__ ad1,
                       const float* __restrict__ Wa2, const float* __restrict__ as2,
                       const float* __restrict__ ad2,
                       const float* __restrict__ Wb1, const float* __restrict__ asb1,
                       const float* __restrict__ adb1,
                       const float* __restrict__ Wb2, const float* __restrict__ asb2,
                       const float* __restrict__ adb2,
                       int* __restrict__ deg,
                       ushort_t* __restrict__ imgA2, ushort_t* __restrict__ imgB1,
                       ushort_t* __restrict__ imgB2,
                       ushort_t* __restrict__ Wbf, float* __restrict__ esT,
                       float* __restrict__ edT){
    int bid = blockIdx.x, tid = threadIdx.x;
    if(bid < PB_A2){
        ((uint4*)deg)[(bid - PB_ZERO)*256 + tid] = (uint4){0,0,0,0};
    } else if(bid < PB_B1 || (bid >= PB_B2 && bid < PB_WA1)){
        bool isB2 = (bid >= PB_B2);
        int j = (bid - (isB2 ? PB_B2 : PB_A2))*256 + tid;
        if(j < IMG_A2_ELEMS){
            const float* W  = isB2 ? Wb2 : Wa2;
            const float* as = isB2 ? asb2 : as2;
            const float* ad = isB2 ? adb2 : ad2;
            int n = j / 168, k = j - n*168;
            float v = 0.f;
            if(k < 160){
                if(n < 128) v = W[k*128 + n];
                else if(n < 130){
                    const float* av = (n == 128) ? as : ad;
                    float s = 0.f;
                    for(int c=0; c<128; ++c) s += W[k*128 + c]*av[c];
                    v = s;
                }
            }
            (isB2 ? imgB2 : imgA2)[j] = f2bf(v);
        }
    } else if(bid < PB_B2){
        int j = (bid - PB_B1)*256 + tid;
        if(j < IMG_B1_ELEMS){
            int n = j / 136, k = j - n*136;
            float v = 0.f;
            if(k < 128){
                if(n < 160) v = Wb1[k*160 + n];
                else {
                    int j2 = n - 160, h = j2 & 7;
                    const float* av = ((j2 < 8) ? asb1 : adb1) + h*F1;
                    const float* wr = Wb1 + k*160 + h*F1;
                    float s = 0.f;
                    #pragma unroll
                    for(int f=0; f<F1; ++f) s += wr[f]*av[f];
                    v = s;
                }
            }
            imgB1[j] = f2bf(v);
        }
    } else if(bid < PB_EST){
        int j = (bid - PB_WA1)*256 + tid;
        if(j < NLBL*D160) Wbf[j] = f2bf(Wa1[j]);
    } else {
        int t = (bid - PB_EST)*256 + tid;
        if(t < NLBL*16){
            int lbl = t >> 4, j = t & 15, h = j & 7;
            const float* av = ((j < 8) ? as1 : ad1) + h*F1;
            const float* wr = Wa1 + lbl*D160 + h*F1;
            float s = 0.f;
            #pragma unroll
            for(int f=0; f<F1; ++f) s += wr[f]*av[f];
            if(j < 8) esT[lbl*8 + h] = s;
            else      edT[lbl*8 + h] = s;
        }
    }
}

// ---------------- ELL adjacency build (dst -> list of src) ----------------
__global__ void k_build_ell(const int* __restrict__ src, const int* __restrict__ dst,
                            int* __restrict__ deg, int* __restrict__ ell){
    int blk = xswz(blockIdx.x, E_EDGES/256);
    int e = blk*blockDim.x + threadIdx.x;
    int d = dst[e];
    int p = atomicAdd(&deg[d], 1);
    if(p < MAXDEG) ell[d*MAXDEG + p] = src[e];
}

// ---------------- layer A fused z-gen + 8-head attention (LDS table; no-max softmax) ----
__global__ __launch_bounds__(256) void k_attn8_a(const int* __restrict__ x,
        const int* __restrict__ deg, const int* __restrict__ ell,
        const ushort_t* __restrict__ Wbf, const float* __restrict__ esT,
        const float* __restrict__ edT, const float* __restrict__ bias,
        ushort_t* __restrict__ out){
    __shared__ __align__(16) ushort_t Wl[NLBL*D160];   // 32000 B
    __shared__ float esL[NLBL*8], edL[NLBL*8];         // 2x3200 B
    int tid = threadIdx.x;
    for(int i = tid; i < NLBL*D160/8; i += 256)
        ((uint4*)Wl)[i] = ((const uint4*)Wbf)[i];
    for(int i = tid; i < NLBL*8; i += 256){ esL[i] = esT[i]; edL[i] = edT[i]; }
    __syncthreads();
    int blk = xswz(blockIdx.x, N_NODES*NHEADS/256);
    int t = blk*256 + tid;
    int n = t >> 3, h = t & 7;
    int dg = deg[n]; if(dg > MAXDEG) dg = MAXDEG;
    int lbl = x[n];
    float edn = edL[lbl*8 + h];
    float wself = expf(lrelu(esL[lbl*8 + h] + edn));
    float den = wself;
    float acc[F1];
    {
        const uint_t* zn = (const uint_t*)Wl + lbl*80 + h*10;
        #pragma unroll
        for(int f=0; f<10; ++f){
            uint_t v = zn[f];
            acc[2*f]   = wself*bflo(v);
            acc[2*f+1] = wself*bfhi(v);
        }
    }
    const int* el = ell + n*MAXDEG;
    int i = 0;
    for(; i+2 <= dg; i += 2){
        int sa = el[i], sb = el[i+1];
        int la = x[sa], lb = x[sb];
        float wa = expf(lrelu(esL[la*8 + h] + edn));
        float wb = expf(lrelu(esL[lb*8 + h] + edn));
        den += wa + wb;
        const uint_t* za = (const uint_t*)Wl + la*80 + h*10;
        const uint_t* zb = (const uint_t*)Wl + lb*80 + h*10;
        #pragma unroll
        for(int f=0; f<10; ++f){
            uint_t va = za[f], vb = zb[f];
            acc[2*f]   += wa*bflo(va) + wb*bflo(vb);
            acc[2*f+1] += wa*bfhi(va) + wb*bfhi(vb);
        }
    }
    if(i < dg){
        int sa = el[i];
        int la = x[sa];
        float wa = expf(lrelu(esL[la*8 + h] + edn));
        den += wa;
        const uint_t* za = (const uint_t*)Wl + la*80 + h*10;
        #pragma unroll
        for(int f=0; f<10; ++f){
            uint_t va = za[f];
            acc[2*f]   += wa*bflo(va);
            acc[2*f+1] += wa*bfhi(va);
        }
    }
    float inv = 1.f/(den + 1e-16f);
    uint_t* o = (uint_t*)(out + (size_t)n*D160 + h*F1);
    const float* bb = bias + h*F1;
    #pragma unroll
    for(int f=0; f<10; ++f){
        float v0 = fmaxf(acc[2*f]*inv   + bb[2*f],   0.f);
        float v1 = fmaxf(acc[2*f+1]*inv + bb[2*f+1], 0.f);
        o[f] = (uint_t)f2bf(v0) | ((uint_t)f2bf(v1) << 16);
    }
}

// ---------------- 8-head attention (layer B): single pass, no-max softmax ----------------
__global__ void k_attn8(const int* __restrict__ deg, const int* __restrict__ ell,
                        const ushort_t* __restrict__ z8, const float* __restrict__ es8,
                        const float* __restrict__ ed8, const float* __restrict__ bias,
                        ushort_t* __restrict__ out){
    int blk = xswz(blockIdx.x, N_NODES*NHEADS/256);
    int t = blk*blockDim.x + threadIdx.x;
    int n = t >> 3, h = t & 7;
    int dg = deg[n]; if(dg > MAXDEG) dg = MAXDEG;
    float edn = ed8[t];
    float wself = expf(lrelu(es8[t] + edn));
    float den = wself;
    float acc[F1];
    const uint_t* zn = (const uint_t*)(z8 + (size_t)n*D160 + h*F1);
    #pragma unroll
    for(int f=0; f<10; ++f){
        uint_t v = zn[f];
        acc[2*f]   = wself*bflo(v);
        acc[2*f+1] = wself*bfhi(v);
    }
    const int* el = ell + n*MAXDEG;
    int i = 0;
    for(; i+2 <= dg; i += 2){
        int sa = el[i], sb = el[i+1];
        float ea = es8[sa*NHEADS + h], eb = es8[sb*NHEADS + h];
        const uint_t* za = (const uint_t*)(z8 + (size_t)sa*D160 + h*F1);
        const uint_t* zb = (const uint_t*)(z8 + (size_t)sb*D160 + h*F1);
        float wa = expf(lrelu(ea + edn));
        float wb = expf(lrelu(eb + edn));
        den += wa + wb;
        #pragma unroll
        for(int f=0; f<10; ++f){
            uint_t va = za[f], vb = zb[f];
            acc[2*f]   += wa*bflo(va) + wb*bflo(vb);
            acc[2*f+1] += wa*bfhi(va) + wb*bfhi(vb);
        }
    }
    if(i < dg){
        int sa = el[i];
        float ea = es8[sa*NHEADS + h];
        const uint_t* za = (const uint_t*)(z8 + (size_t)sa*D160 + h*F1);
        float wa = expf(lrelu(ea + edn));
        den += wa;
        #pragma unroll
        for(int f=0; f<10; ++f){
            uint_t va = za[f];
            acc[2*f]   += wa*bflo(va);
            acc[2*f+1] += wa*bfhi(va);
        }
    }
    float inv = 1.f/(den + 1e-16f);
    uint_t* o = (uint_t*)(out + (size_t)n*D160 + h*F1);
    const float* bb = bias + h*F1;
    #pragma unroll
    for(int f=0; f<10; ++f){
        float v0 = fmaxf(acc[2*f]*inv   + bb[2*f],   0.f);
        float v1 = fmaxf(acc[2*f+1]*inv + bb[2*f+1], 0.f);
        o[f] = (uint_t)f2bf(v0) | ((uint_t)f2bf(v1) << 16);
    }
}

// ---------------- MFMA GEMM from prebuilt bf16 image; es/ed from last fragment ----------
// ESED8=false: oa/ob are es1/ed1 (image rows OUTC..OUTC+1).
// ESED8=true : oa/ob are es8/ed8 [N,8]  (image rows 160..175).
template<int IN, int OUTC, int OUTIMG, bool ESED8>
__global__ __launch_bounds__(256) void k_gemm2(const ushort_t* __restrict__ Wimg,
                                               const ushort_t* __restrict__ A,
                                               ushort_t* __restrict__ C,
                                               float* __restrict__ oa,
                                               float* __restrict__ ob){
    constexpr int LDW = IN + 8;
    constexpr int NT = OUTIMG/16;
    constexpr int NC = OUTC/16;
    constexpr int KS = IN/32;
    constexpr int ELEMS = OUTIMG*LDW;
    __shared__ __align__(16) ushort_t Wt[ELEMS];
    int tid = threadIdx.x;
    int blk = xswz(blockIdx.x, N_NODES/64);
    int wave = tid >> 6, lane = tid & 63;
    int col16 = lane & 15;
    int kq = (lane >> 4) * 8;
    int row = blk*64 + wave*16 + col16;
    const ushort_t* Ar = A + (size_t)row*IN + kq;
    short8 afr[KS];
    #pragma unroll
    for(int ks=0; ks<KS; ++ks)
        afr[ks] = *reinterpret_cast<const short8*>(Ar + ks*32);
    for(int i = tid; i < ELEMS/8; i += 256)
        ((uint4*)Wt)[i] = ((const uint4*)Wimg)[i];
    __syncthreads();
    f32x4 acc[NT];
    #pragma unroll
    for(int c=0;c<NT;++c) acc[c] = (f32x4){0.f,0.f,0.f,0.f};
    #pragma unroll
    for(int ks=0; ks<KS; ++ks){
        #pragma unroll
        for(int c=0;c<NT;++c){
            short8 bf = *reinterpret_cast<const short8*>(&Wt[(c*16 + col16)*LDW + ks*32 + kq]);
            acc[c] = __builtin_amdgcn_mfma_f32_16x16x32_bf16(afr[ks], bf, acc[c], 0, 0, 0);
        }
    }
    int rbase = blk*64 + wave*16 + (lane >> 4)*4;
    #pragma unroll
    for(int c=0;c<NC;++c){
        #pragma unroll
        for(int r=0;r<4;++r){
            C[(size_t)(rbase + r)*OUTC + c*16 + col16] = f2bf(acc[c][r]);
        }
    }
    if(ESED8){
        #pragma unroll
        for(int r=0;r<4;++r){
            float v = acc[NT-1][r];
            if(col16 < 8) oa[(size_t)(rbase + r)*8 + col16] = v;
            else          ob[(size_t)(rbase + r)*8 + (col16 - 8)] = v;
        }
    } else {
        if(col16 == 0){
            #pragma unroll
            for(int r=0;r<4;++r) oa[rbase + r] = acc[NT-1][r];
        }
        if(col16 == 1){
            #pragma unroll
            for(int r=0;r<4;++r) ob[rbase + r] = acc[NT-1][r];
        }
    }
}

// ---------------- 1-head attention aggregate (wave per node), no-max softmax ----------------
template<typename OutT, bool DOT>
__global__ void k_attn1(const int* __restrict__ deg, const int* __restrict__ ell,
                        const ushort_t* __restrict__ Z, const float* __restrict__ es,
                        const float* __restrict__ ed, const float* __restrict__ bias,
                        OutT* __restrict__ out,
                        const float* __restrict__ wa, const float* __restrict__ wb,
                        float* __restrict__ oa, float* __restrict__ ob){
    int blk = xswz(blockIdx.x, N_NODES/4);
    int gt = blk*blockDim.x + threadIdx.x;
    int n = gt >> 6;
    int l = threadIdx.x & 63;
    int dg = deg[n]; if(dg > MAXDEG) dg = MAXDEG;
    float edn = ed[n];
    float wself = expf(lrelu(es[n] + edn));
    int s_l = 0; float w_l = 0.f;
    if(l < dg){ s_l = ell[n*MAXDEG + l]; w_l = expf(lrelu(es[s_l] + edn)); }
    float den = w_l;
    for(int o=32;o>0;o>>=1) den += __shfl_xor(den,o);
    den += wself;
    const uint_t* Zu = (const uint_t*)Z;
    uint_t zn = Zu[(size_t)n*64 + l];
    float acc0 = wself*bflo(zn);
    float acc1 = wself*bfhi(zn);
    int i = 0;
    for(; i+4 <= dg; i += 4){
        int s0 = __builtin_amdgcn_readlane(s_l, i);
        int s1 = __builtin_amdgcn_readlane(s_l, i+1);
        int s2 = __builtin_amdgcn_readlane(s_l, i+2);
        int s3 = __builtin_amdgcn_readlane(s_l, i+3);
        uint_t z0 = Zu[(size_t)s0*64 + l];
        uint_t z1 = Zu[(size_t)s1*64 + l];
        uint_t z2 = Zu[(size_t)s2*64 + l];
        uint_t z3 = Zu[(size_t)s3*64 + l];
        float w0 = rdlanef(w_l, i);
        float w1 = rdlanef(w_l, i+1);
        float w2 = rdlanef(w_l, i+2);
        float w3 = rdlanef(w_l, i+3);
        acc0 += w0*bflo(z0) + w1*bflo(z1);
        acc1 += w0*bfhi(z0) + w1*bfhi(z1);
        acc0 += w2*bflo(z2) + w3*bflo(z3);
        acc1 += w2*bfhi(z2) + w3*bfhi(z3);
    }
    for(; i < dg; ++i){
        int s0 = __builtin_amdgcn_readlane(s_l, i);
        float w0 = rdlanef(w_l, i);
        uint_t z0 = Zu[(size_t)s0*64 + l];
        acc0 += w0*bflo(z0);
        acc1 += w0*bfhi(z0);
    }
    float inv = 1.f/(den + 1e-16f);
    float2 bb = ((const float2*)bias)[l];
    float r0 = fmaxf(acc0*inv + bb.x, 0.f);
    float r1 = fmaxf(acc1*inv + bb.y, 0.f);
    if(sizeof(OutT) == 2){
        ((uint_t*)out)[(size_t)n*64 + l] = (uint_t)f2bf(r0) | ((uint_t)f2bf(r1) << 16);
    } else {
        float2 rv; rv.x = r0; rv.y = r1;
        ((float2*)out)[(size_t)n*64 + l] = rv;
    }
    if(DOT){
        float2 a2 = ((const float2*)wa)[l];
        float2 b2 = ((const float2*)wb)[l];
        float pa = r0*a2.x + r1*a2.y;
        float pb = r0*b2.x + r1*b2.y;
        for(int o=32;o>0;o>>=1){ pa += __shfl_xor(pa,o); pb += __shfl_xor(pb,o); }
        if(l==0){ oa[n] = pa; ob[n] = pb; }
    }
}

// ---------------- pooling score ----------------
__global__ void k_score(const int* __restrict__ deg, const int* __restrict__ ell,
                        const float* __restrict__ yrel, const float* __restrict__ rroot,
                        const float* __restrict__ bpool, float* __restrict__ score){
    int blk = xswz(blockIdx.x, N_NODES/256);
    int n = blk*blockDim.x + threadIdx.x;
    int dg = deg[n]; if(dg > MAXDEG) dg = MAXDEG;
    float s = rroot[n] + bpool[0];
    const int* el = ell + n*MAXDEG;
    int i = 0;
    for(; i+4 <= dg; i += 4){
        float y0 = yrel[el[i]],   y1 = yrel[el[i+1]];
        float y2 = yrel[el[i+2]], y3 = yrel[el[i+3]];
        s += (y0 + y1) + (y2 + y3);
    }
    for(; i < dg; ++i) s += yrel[el[i]];
    score[n] = tanhf(s);
}

// ---------------- per-graph top-k: single-wave register bitonic + parallel pool ----------------
__global__ __launch_bounds__(512) void k_topk_pool(const float* __restrict__ score,
                                                   const ushort_t* __restrict__ H,
                                                   float* __restrict__ pooled,
                                                   float* __restrict__ perm_f,
                                                   float* __restrict__ sv,
                                                   float* __restrict__ batch_f){
    __shared__ int   sidx[KSEL];
    __shared__ float sval[KSEL];
    __shared__ float pmax[512];
    int g = xswz(blockIdx.x, NGRAPH);
    int base = g*NPG;
    int t = threadIdx.x;
    if(t < 64){
        int l = t;
        u64 v[8];
        #pragma unroll
        for(int r=0;r<8;++r){
            int i = r*64 + l;
            v[r] = comp_make(score[base + i], i);
        }
        #pragma unroll
        for(int kk=1; kk<=9; ++kk){
            int k = 1 << kk;
            #pragma unroll
            for(int jj=kk-1; jj>=0; --jj){
                int j = 1 << jj;
                if(j < 64){
                    bool lower = (l & j) == 0;
                    #pragma unroll
                    for(int r=0;r<8;++r){
                        int i = r*64 + l;
                        u64 p = shfl_xor_u64(v[r], j);
                        bool desc = (i & k) == 0;
                        u64 mx = v[r] > p ? v[r] : p;
                        u64 mn = v[r] > p ? p : v[r];
                        v[r] = (lower == desc) ? mx : mn;
                    }
                } else {
                    int jr = j >> 6;
                    #pragma unroll
                    for(int r=0;r<8;++r){
                        if((r & jr) == 0){
                            int rp = r | jr;
                            int i = r*64 + l;
                            bool desc = (i & k) == 0;
                            u64 a = v[r], b = v[rp];
                            u64 mx = a > b ? a : b;
                            u64 mn = a > b ? b : a;
                            v[r]  = desc ? mx : mn;
                            v[rp] = desc ? mn : mx;
                        }
                    }
                }
            }
        }
        #pragma unroll
        for(int r=0;r<4;++r){
            int i = r*64 + l;
            int idx = comp_idx(v[r]);
            float s = comp_score(v[r]);
            perm_f[g*KSEL + i]  = (float)(base + idx);
            sv[g*KSEL + i]      = s;
            batch_f[g*KSEL + i] = (float)g;
            sidx[i] = idx; sval[i] = s;
        }
    }
    __syncthreads();
    int c = t & 127, kc = t >> 7;
    float mx = -1e30f;
    for(int kk = kc*64; kk < kc*64 + 64; ++kk){
        mx = fmaxf(mx, bf2f(H[(size_t)(base + sidx[kk])*HID + c]) * sval[kk]);
    }
    pmax[t] = mx;
    __syncthreads();
    if(t < HID){
        pooled[g*HID + t] = fmaxf(fmaxf(pmax[t], pmax[t+128]),
                                  fmaxf(pmax[t+256], pmax[t+384]));
    }
}

extern "C" void kernel_launch(void* const* d_in, const int* in_sizes, int n_in,
                              void* d_out, int out_size, void* d_ws, size_t ws_size,
                              hipStream_t stream) {
    const int*   x       = (const int*)  d_in[0];
    const int*   eidx    = (const int*)  d_in[1];
    const float* W_a1    = (const float*)d_in[3];
    const float* asrc_a1 = (const float*)d_in[4];
    const float* adst_a1 = (const float*)d_in[5];
    const float* b_a1    = (const float*)d_in[6];
    const float* W_a2    = (const float*)d_in[7];
    const float* asrc_a2 = (const float*)d_in[8];
    const float* adst_a2 = (const float*)d_in[9];
    const float* b_a2    = (const float*)d_in[10];
    const float* W_b1    = (const float*)d_in[11];
    const float* asrc_b1 = (const float*)d_in[12];
    const float* adst_b1 = (const float*)d_in[13];
    const float* b_b1    = (const float*)d_in[14];
    const float* W_b2    = (const float*)d_in[15];
    const float* asrc_b2 = (const float*)d_in[16];
    const float* adst_b2 = (const float*)d_in[17];
    const float* b_b2    = (const float*)d_in[18];
    const float* w_rel   = (const float*)d_in[19];
    const float* w_root  = (const float*)d_in[20];
    const float* b_pool  = (const float*)d_in[21];

    const int* e_src = eidx;
    const int* e_dst = eidx + E_EDGES;

    char* ws = (char*)d_ws;
    size_t off = 0;
    auto alloc = [&](size_t bytes)->char*{
        char* p = ws + off;
        off += (bytes + 255) & ~(size_t)255;
        return p;
    };
    int*      deg    = (int*)     alloc((size_t)N_NODES*4);
    int*      ell    = (int*)     alloc((size_t)N_NODES*MAXDEG*4);
    ushort_t* z8     = (ushort_t*)alloc((size_t)N_NODES*D160*2);
    ushort_t* h8     = (ushort_t*)alloc((size_t)N_NODES*D160*2);
    ushort_t* zc     = (ushort_t*)alloc((size_t)N_NODES*HID*2);
    ushort_t* hmid   = (ushort_t*)alloc((size_t)N_NODES*HID*2);
    ushort_t* hfin   = (ushort_t*)alloc((size_t)N_NODES*HID*2);
    float*    es8    = (float*)   alloc((size_t)N_NODES*NHEADS*4);
    float*    ed8    = (float*)   alloc((size_t)N_NODES*NHEADS*4);
    float*    es1    = (float*)   alloc((size_t)N_NODES*4);
    float*    ed1    = (float*)   alloc((size_t)N_NODES*4);
    float*    yrel   = (float*)   alloc((size_t)N_NODES*4);
    float*    rroot  = (float*)   alloc((size_t)N_NODES*4);
    float*    score  = (float*)   alloc((size_t)N_NODES*4);
    ushort_t* Wbf    = (ushort_t*)alloc((size_t)NLBL*D160*2);
    float*    esT    = (float*)   alloc((size_t)NLBL*8*4);
    float*    edT    = (float*)   alloc((size_t)NLBL*8*4);
    ushort_t* imgA2  = (ushort_t*)alloc((size_t)IMG_A2_ELEMS*2);
    ushort_t* imgB1  = (ushort_t*)alloc((size_t)IMG_B1_ELEMS*2);
    ushort_t* imgB2  = (ushort_t*)alloc((size_t)IMG_A2_ELEMS*2);
    (void)ws_size; (void)n_in; (void)in_sizes; (void)out_size;

    float* out      = (float*)d_out;
    float* pooled   = out;
    float* perm_f   = out + NGRAPH*HID;
    float* sv       = perm_f + NGRAPH*KSEL;
    float* batch_f  = sv + NGRAPH*KSEL;

    // one prep kernel: zero deg + 3 GEMM weight images + layer-A tables
    k_prep<<<PB_TOT, 256, 0, stream>>>(W_a1, asrc_a1, adst_a1,
                                       W_a2, asrc_a2, adst_a2,
                                       W_b1, asrc_b1, adst_b1,
                                       W_b2, asrc_b2, adst_b2,
                                       deg, imgA2, imgB1, imgB2, Wbf, esT, edT);
    k_build_ell<<<E_EDGES/256, 256, 0, stream>>>(e_src, e_dst, deg, ell);

    // ---- GATNet A, conv1: fused table-attention ----
    k_attn8_a<<<N_NODES*NHEADS/256, 256, 0, stream>>>(x, deg, ell, Wbf, esT, edT, b_a1, h8);

    // ---- GATNet A, conv2 (160 -> 128) + es1/ed1 via extra image cols ----
    k_gemm2<D160, HID, 144, false><<<N_NODES/64, 256, 0, stream>>>(imgA2, h8, zc, es1, ed1);
    k_attn1<ushort_t, false><<<N_NODES/4, 256, 0, stream>>>(deg, ell, zc, es1, ed1, b_a2, hmid,
                                                            nullptr, nullptr, nullptr, nullptr);

    // ---- GATNet B, conv1 (128 -> 20x8) + es8/ed8 via extra image cols ----
    k_gemm2<HID, D160, 176, true><<<N_NODES/64, 256, 0, stream>>>(imgB1, hmid, z8, es8, ed8);
    k_attn8<<<N_NODES*NHEADS/256, 256, 0, stream>>>(deg, ell, z8, es8, ed8, b_b1, h8);

    // ---- GATNet B, conv2 (160 -> 128) + es1/ed1 via extra image cols ----
    k_gemm2<D160, HID, 144, false><<<N_NODES/64, 256, 0, stream>>>(imgB2, h8, zc, es1, ed1);
    // final attention (bf16 out) + fused pooling dots (yrel, rroot)
    k_attn1<ushort_t, true><<<N_NODES/4, 256, 0, stream>>>(deg, ell, zc, es1, ed1, b_b2, hfin,
                                                           w_rel, w_root, yrel, rroot);

    // ---- SAGPooling ----
    k_score<<<N_NODES/256, 256, 0, stream>>>(deg, ell, yrel, rroot, b_pool, score);
    k_topk_pool<<<NGRAPH, NPG, 0, stream>>>(score, hfin, pooled, perm_f, sv, batch_f);
}